// Round 2
// baseline (496.184 us; speedup 1.0000x reference)
//
#include <hip/hip_runtime.h>
#include <math.h>

#define N_NODES 100000
#define N_EDGES 3200000
#define IN_F 256
#define OUT_F 64
#define LRELU_ALPHA 0.2f
#define NBKT 782   // ceil(100000/128) coarse buckets of 128 nodes
#define CAP 4480   // bucket capacity: mean 4096 + 6 sigma (sigma=64)

typedef unsigned short u16;
typedef __attribute__((ext_vector_type(8))) short short8;
typedef __attribute__((ext_vector_type(4))) float floatx4;

__device__ inline u16 f2bf(float f) {  // RNE fp32 -> bf16
  unsigned u = __float_as_uint(f);
  u += 0x7FFFu + ((u >> 16) & 1u);
  return (u16)(u >> 16);
}
__device__ inline float bf2f(u16 h) {
  return __uint_as_float(((unsigned)h) << 16);
}

// ---------------------------------------------------------------------------
// prep: blocks 0..63 convert W to bf16; blocks 64..163 zero the contiguous
// sfill+denom region (100,800 words) with int4 stores. No host memset —
// graph-capture-safe.
// ---------------------------------------------------------------------------
#define ZERO_WORDS (800 + 100000)
__global__ __launch_bounds__(256) void k_prep(const float* __restrict__ W,
                                              u16* __restrict__ Wbf,
                                              int* __restrict__ zbase) {
  if (blockIdx.x < 64) {
    int i = blockIdx.x * 256 + threadIdx.x;
    Wbf[i] = f2bf(W[i]);
  } else {
    int i4 = (blockIdx.x - 64) * 256 + threadIdx.x;  // float4 index
    if (i4 < ZERO_WORDS / 4) {
      ((int4*)zbase)[i4] = make_int4(0, 0, 0, 0);
    }
  }
}

// ---------------------------------------------------------------------------
// linear via bf16 MFMA: h = x@W^T + b (stored bf16); s1 = h.a1; s2 = h.a2
// ---------------------------------------------------------------------------
__global__ __launch_bounds__(256) void k_linear(
    const float* __restrict__ x, const u16* __restrict__ Wbf,
    const float* __restrict__ b, const float* __restrict__ a,
    u16* __restrict__ hbf, float* __restrict__ s1, float* __restrict__ s2) {
  __shared__ u16 Wlds[64 * 264];

  const int t = threadIdx.x;
#pragma unroll
  for (int p = 0; p < 8; p++) {
    int c = p * 256 + t;
    int row = c >> 5;
    int kc = (c & 31) * 8;
    *(short8*)&Wlds[row * 264 + kc] = *(const short8*)&Wbf[row * 256 + kc];
  }
  __syncthreads();

  const int w = t >> 6;
  const int lane = t & 63;
  const int col = lane & 15;
  const int q = lane >> 4;
  const int m0 = blockIdx.x * 64 + w * 16;

  floatx4 acc[4];
#pragma unroll
  for (int nt = 0; nt < 4; nt++) acc[nt] = (floatx4){0.f, 0.f, 0.f, 0.f};

  int mrow = m0 + col;
  if (mrow > N_NODES - 1) mrow = N_NODES - 1;
  const float* xrow = x + (size_t)mrow * IN_F + q * 8;

#pragma unroll
  for (int kk = 0; kk < 8; kk++) {
    float4 f0 = *(const float4*)(xrow + kk * 32);
    float4 f1 = *(const float4*)(xrow + kk * 32 + 4);
    short8 af;
    af[0] = (short)f2bf(f0.x);
    af[1] = (short)f2bf(f0.y);
    af[2] = (short)f2bf(f0.z);
    af[3] = (short)f2bf(f0.w);
    af[4] = (short)f2bf(f1.x);
    af[5] = (short)f2bf(f1.y);
    af[6] = (short)f2bf(f1.z);
    af[7] = (short)f2bf(f1.w);
#pragma unroll
    for (int nt = 0; nt < 4; nt++) {
      short8 bfr = *(const short8*)&Wlds[(nt * 16 + col) * 264 + kk * 32 + q * 8];
      acc[nt] = __builtin_amdgcn_mfma_f32_16x16x32_bf16(af, bfr, acc[nt], 0, 0, 0);
    }
  }

  float bv[4], a1v[4], a2v[4];
#pragma unroll
  for (int nt = 0; nt < 4; nt++) {
    bv[nt] = b[nt * 16 + col];
    a1v[nt] = a[nt * 16 + col];
    a2v[nt] = a[OUT_F + nt * 16 + col];
  }
#pragma unroll
  for (int r = 0; r < 4; r++) {
    int node = m0 + q * 4 + r;
    float p1 = 0.f, p2 = 0.f;
#pragma unroll
    for (int nt = 0; nt < 4; nt++) {
      float hv = acc[nt][r] + bv[nt];
      if (node < N_NODES) hbf[(size_t)node * OUT_F + nt * 16 + col] = f2bf(hv);
      p1 = fmaf(hv, a1v[nt], p1);
      p2 = fmaf(hv, a2v[nt], p2);
    }
#pragma unroll
    for (int s = 1; s < 16; s <<= 1) {
      p1 += __shfl_xor(p1, s, 16);
      p2 += __shfl_xor(p2, s, 16);
    }
    if (col == 0 && node < N_NODES) {
      s1[node] = p1;
      s2[node] = p2;
    }
  }
}

// ---------------------------------------------------------------------------
// place: ex = exp(leakyrelu(s1[src]+s2[dst])); write into PADDED src buckets
// (bucket b occupies [b*CAP, b*CAP + fill[b])). One global atomic per
// (block,bucket) chunk reservation; LDS atomics for ranks. The dst-side
// segment-sum (softmax denominator) is fused here as fire-and-forget global
// fp32 atomics into denom[] -- no pairD array, no k_denom kernel.
// pairS = (ex, d | (s&127)<<17)  src-bucketed
// ---------------------------------------------------------------------------
#define EPT_P 8
__global__ __launch_bounds__(1024) void k_place(
    const int* __restrict__ src, const int* __restrict__ dst,
    const float* __restrict__ s1, const float* __restrict__ s2,
    int* __restrict__ sfill, float* __restrict__ denom,
    float2* __restrict__ pairS) {
  __shared__ int lcS[NBKT];
  __shared__ int lbS[NBKT];
  const int t = threadIdx.x;
  for (int i = t; i < NBKT; i += 1024) lcS[i] = 0;
  __syncthreads();

  int base = blockIdx.x * (1024 * EPT_P) + t;
  float ex[EPT_P];
  int pk[EPT_P];
  int bs[EPT_P];
#pragma unroll
  for (int j = 0; j < EPT_P; j++) {
    int e = base + j * 1024;
    if (e < N_EDGES) {
      int s = src[e];
      int d = dst[e];
      float v = s1[s] + s2[d];
      v = v > 0.f ? v : LRELU_ALPHA * v;
      ex[j] = __expf(v);
      pk[j] = d | ((s & 127) << 17);
      bs[j] = s >> 7;
      atomicAdd(&lcS[bs[j]], 1);
    }
  }
  __syncthreads();
  for (int i = t; i < NBKT; i += 1024) {
    int c = lcS[i];
    if (c) lbS[i] = atomicAdd(&sfill[i], c);
  }
  __syncthreads();
  for (int i = t; i < NBKT; i += 1024) lcS[i] = 0;
  __syncthreads();
#pragma unroll
  for (int j = 0; j < EPT_P; j++) {
    int e = base + j * 1024;
    if (e < N_EDGES) {
      int d = pk[j] & 0x1FFFF;
      atomicAdd(&denom[d], ex[j]);
      int r = atomicAdd(&lcS[bs[j]], 1);
      pairS[(size_t)bs[j] * CAP + lbS[bs[j]] + r] =
          make_float2(ex[j], __int_as_float(pk[j]));
    }
  }
}

// ---------------------------------------------------------------------------
// sort2: block per src-bucket. Exact node-sort within the bucket via LDS
// histogram + scan + LDS-atomic rank. Folds att = ex * rcp(denom[d]).
// Emits rowbe[node] = (beg,end) into padded pairA space.
// ---------------------------------------------------------------------------
__global__ __launch_bounds__(256) void k_sort2(
    const int* __restrict__ sfill, const float2* __restrict__ pairS,
    const float* __restrict__ denom, float2* __restrict__ pairA,
    int2* __restrict__ rowbe) {
  __shared__ int lcnt[128];
  __shared__ int cursor[128];
  __shared__ int w0tot;
  const int t = threadIdx.x;
  const int bkt = blockIdx.x;
  if (t < 128) lcnt[t] = 0;
  __syncthreads();

  const int beg = bkt * CAP;
  const int end = beg + sfill[bkt];

  for (int i = beg + t; i < end; i += 256) {
    int pkv = __float_as_int(pairS[i].y);
    atomicAdd(&lcnt[(pkv >> 17) & 127], 1);
  }
  __syncthreads();

  const int lane = t & 63;
  int v = (t < 128) ? lcnt[t] : 0;
  int val = v;
#pragma unroll
  for (int ofs = 1; ofs < 64; ofs <<= 1) {
    int u = __shfl_up(val, ofs, 64);
    if (lane >= ofs) val += u;
  }
  if (t == 63) w0tot = val;
  __syncthreads();
  int excl = val - v + ((t >= 64 && t < 128) ? w0tot : 0);
  if (t < 128) {
    cursor[t] = beg + excl;
    int node = bkt * 128 + t;
    if (node < N_NODES) rowbe[node] = make_int2(beg + excl, beg + excl + v);
  }
  __syncthreads();

  for (int i = beg + t; i < end; i += 256) {
    float2 p = pairS[i];
    int pkv = __float_as_int(p.y);
    int sl = (pkv >> 17) & 127;
    int d = pkv & 0x1FFFF;
    float att = p.x * __builtin_amdgcn_rcpf(denom[d]);
    int pos = atomicAdd(&cursor[sl], 1);
    pairA[pos] = make_float2(att, __int_as_float(d));
  }
}

// ---------------------------------------------------------------------------
// aggregate: 4 nodes per wave (16 lanes/node, ushort4 = 4 features/lane).
// Each vmem instruction services 4 edges. Register acc, 2-wide unroll, elu.
// ---------------------------------------------------------------------------
__global__ __launch_bounds__(256) void k_aggregate(
    const int2* __restrict__ rowbe, const float2* __restrict__ pairA,
    const u16* __restrict__ hbf, float* __restrict__ out) {
  int wid = (blockIdx.x * 256 + threadIdx.x) >> 6;
  int lane = threadIdx.x & 63;
  int g = lane >> 4;
  int sl = lane & 15;
  int node = wid * 4 + g;
  int2 be = (node < N_NODES) ? rowbe[node] : make_int2(0, 0);
  float4 acc = make_float4(0.f, 0.f, 0.f, 0.f);
  int i = be.x;
  const int end = be.y;
  for (; i + 1 < end; i += 2) {
    float2 p0 = pairA[i];
    float2 p1 = pairA[i + 1];
    int d0 = __float_as_int(p0.y);
    int d1 = __float_as_int(p1.y);
    ushort4 q0 = *(const ushort4*)&hbf[(size_t)d0 * OUT_F + sl * 4];
    ushort4 q1 = *(const ushort4*)&hbf[(size_t)d1 * OUT_F + sl * 4];
    acc.x = fmaf(p0.x, bf2f(q0.x), acc.x);
    acc.y = fmaf(p0.x, bf2f(q0.y), acc.y);
    acc.z = fmaf(p0.x, bf2f(q0.z), acc.z);
    acc.w = fmaf(p0.x, bf2f(q0.w), acc.w);
    acc.x = fmaf(p1.x, bf2f(q1.x), acc.x);
    acc.y = fmaf(p1.x, bf2f(q1.y), acc.y);
    acc.z = fmaf(p1.x, bf2f(q1.z), acc.z);
    acc.w = fmaf(p1.x, bf2f(q1.w), acc.w);
  }
  if (i < end) {
    float2 p = pairA[i];
    int d = __float_as_int(p.y);
    ushort4 q = *(const ushort4*)&hbf[(size_t)d * OUT_F + sl * 4];
    acc.x = fmaf(p.x, bf2f(q.x), acc.x);
    acc.y = fmaf(p.x, bf2f(q.y), acc.y);
    acc.z = fmaf(p.x, bf2f(q.z), acc.z);
    acc.w = fmaf(p.x, bf2f(q.w), acc.w);
  }
  if (node < N_NODES) {
    float4 o;
    o.x = acc.x > 0.f ? acc.x : expm1f(acc.x);
    o.y = acc.y > 0.f ? acc.y : expm1f(acc.y);
    o.z = acc.z > 0.f ? acc.z : expm1f(acc.z);
    o.w = acc.w > 0.f ? acc.w : expm1f(acc.w);
    *(float4*)(out + (size_t)node * OUT_F + sl * 4) = o;
  }
}

// ---------------------------------------------------------------------------
extern "C" void kernel_launch(void* const* d_in, const int* in_sizes, int n_in,
                              void* d_out, int out_size, void* d_ws,
                              size_t ws_size, hipStream_t stream) {
  const int* adj = (const int*)d_in[0];
  const float* x = (const float*)d_in[1];
  const float* W = (const float*)d_in[2];
  const float* b = (const float*)d_in[3];
  const float* a = (const float*)d_in[4];
  float* out = (float*)d_out;

  float* ws = (float*)d_ws;
  float* s1v = ws;                            // 100,000
  float* s2v = ws + 100000;                   // 100,000
  int* sfill = (int*)(ws + 200000);           // 782 (pad 800)   } zeroed by
  float* denom = ws + 200800;                 // 100,000         } k_prep
  int2* rowbe = (int2*)(ws + 300800);         // 100,000 int2 = 200,000 f
  float2* pairS = (float2*)(ws + 500800);     // 782*4480 float2 = 7,006,720 f
  float2* pairA = (float2*)(ws + 7507520);    // 782*4480 float2
  u16* hbf = (u16*)(ws + 14514240);           // 6.4M u16 = 3.2M f
  u16* Wbf = (u16*)(ws + 17714240);           // 16,384 u16
  // total ~17.72M floats = 70.9 MB

  const int* src = adj;
  const int* dst = adj + N_EDGES;

  // grid = 64 (W convert) + 100 (zero sfill+denom: 25,200 int4 stores)
  k_prep<<<164, 256, 0, stream>>>(W, Wbf, sfill);
  k_linear<<<(N_NODES + 63) / 64, 256, 0, stream>>>(x, Wbf, b, a, hbf, s1v, s2v);
  k_place<<<(N_EDGES + 1024 * EPT_P - 1) / (1024 * EPT_P), 1024, 0, stream>>>(
      src, dst, s1v, s2v, sfill, denom, pairS);
  k_sort2<<<NBKT, 256, 0, stream>>>(sfill, pairS, denom, pairA, rowbe);
  k_aggregate<<<(N_NODES + 15) / 16, 256, 0, stream>>>(rowbe, pairA, hbf, out);
}

// Round 3
// 409.879 us; speedup vs baseline: 1.2106x; 1.2106x over previous
//
#include <hip/hip_runtime.h>
#include <math.h>

#define N_NODES 100000
#define N_EDGES 3200000
#define IN_F 256
#define OUT_F 64
#define LRELU_ALPHA 0.2f
#define NBKT 782   // ceil(100000/128) coarse buckets of 128 nodes
#define CAP 4480   // bucket capacity: mean 4096 + 6 sigma (sigma=64)

typedef unsigned short u16;
typedef __attribute__((ext_vector_type(8))) short short8;
typedef __attribute__((ext_vector_type(4))) float floatx4;

__device__ inline u16 f2bf(float f) {  // RNE fp32 -> bf16
  unsigned u = __float_as_uint(f);
  u += 0x7FFFu + ((u >> 16) & 1u);
  return (u16)(u >> 16);
}
__device__ inline float bf2f(u16 h) {
  return __uint_as_float(((unsigned)h) << 16);
}

// ---------------------------------------------------------------------------
// prep: blocks 0..63 convert W to bf16; block 64 zeros the bucket fill ctrs
// ---------------------------------------------------------------------------
__global__ __launch_bounds__(256) void k_prep(const float* __restrict__ W,
                                              u16* __restrict__ Wbf,
                                              int* __restrict__ sfill,
                                              int* __restrict__ dfill) {
  if (blockIdx.x < 64) {
    int i = blockIdx.x * 256 + threadIdx.x;
    Wbf[i] = f2bf(W[i]);
  } else {
    for (int i = threadIdx.x; i < NBKT; i += 256) {
      sfill[i] = 0;
      dfill[i] = 0;
    }
  }
}

// ---------------------------------------------------------------------------
// linear via bf16 MFMA: h = x@W^T + b (stored bf16); s1 = h.a1; s2 = h.a2
// ---------------------------------------------------------------------------
__global__ __launch_bounds__(256) void k_linear(
    const float* __restrict__ x, const u16* __restrict__ Wbf,
    const float* __restrict__ b, const float* __restrict__ a,
    u16* __restrict__ hbf, float* __restrict__ s1, float* __restrict__ s2) {
  __shared__ u16 Wlds[64 * 264];

  const int t = threadIdx.x;
#pragma unroll
  for (int p = 0; p < 8; p++) {
    int c = p * 256 + t;
    int row = c >> 5;
    int kc = (c & 31) * 8;
    *(short8*)&Wlds[row * 264 + kc] = *(const short8*)&Wbf[row * 256 + kc];
  }
  __syncthreads();

  const int w = t >> 6;
  const int lane = t & 63;
  const int col = lane & 15;
  const int q = lane >> 4;
  const int m0 = blockIdx.x * 64 + w * 16;

  floatx4 acc[4];
#pragma unroll
  for (int nt = 0; nt < 4; nt++) acc[nt] = (floatx4){0.f, 0.f, 0.f, 0.f};

  int mrow = m0 + col;
  if (mrow > N_NODES - 1) mrow = N_NODES - 1;
  const float* xrow = x + (size_t)mrow * IN_F + q * 8;

#pragma unroll
  for (int kk = 0; kk < 8; kk++) {
    float4 f0 = *(const float4*)(xrow + kk * 32);
    float4 f1 = *(const float4*)(xrow + kk * 32 + 4);
    short8 af;
    af[0] = (short)f2bf(f0.x);
    af[1] = (short)f2bf(f0.y);
    af[2] = (short)f2bf(f0.z);
    af[3] = (short)f2bf(f0.w);
    af[4] = (short)f2bf(f1.x);
    af[5] = (short)f2bf(f1.y);
    af[6] = (short)f2bf(f1.z);
    af[7] = (short)f2bf(f1.w);
#pragma unroll
    for (int nt = 0; nt < 4; nt++) {
      short8 bfr = *(const short8*)&Wlds[(nt * 16 + col) * 264 + kk * 32 + q * 8];
      acc[nt] = __builtin_amdgcn_mfma_f32_16x16x32_bf16(af, bfr, acc[nt], 0, 0, 0);
    }
  }

  float bv[4], a1v[4], a2v[4];
#pragma unroll
  for (int nt = 0; nt < 4; nt++) {
    bv[nt] = b[nt * 16 + col];
    a1v[nt] = a[nt * 16 + col];
    a2v[nt] = a[OUT_F + nt * 16 + col];
  }
#pragma unroll
  for (int r = 0; r < 4; r++) {
    int node = m0 + q * 4 + r;
    float p1 = 0.f, p2 = 0.f;
#pragma unroll
    for (int nt = 0; nt < 4; nt++) {
      float hv = acc[nt][r] + bv[nt];
      if (node < N_NODES) hbf[(size_t)node * OUT_F + nt * 16 + col] = f2bf(hv);
      p1 = fmaf(hv, a1v[nt], p1);
      p2 = fmaf(hv, a2v[nt], p2);
    }
#pragma unroll
    for (int s = 1; s < 16; s <<= 1) {
      p1 += __shfl_xor(p1, s, 16);
      p2 += __shfl_xor(p2, s, 16);
    }
    if (col == 0 && node < N_NODES) {
      s1[node] = p1;
      s2[node] = p2;
    }
  }
}

// ---------------------------------------------------------------------------
// place: ex = exp(leakyrelu(s1[src]+s2[dst])); write into PADDED buckets
// (bucket b occupies [b*CAP, b*CAP + fill[b])).
// NEW: block-local LDS staging + coalesced flush. Per block of 4096 edges:
//   1. LDS histogram per bucket
//   2. reserve global range (1 int atomic / nonempty bucket) AND a block-
//      local contiguous stage range (LDS atomicAdd on `tot`; bucket order
//      in stage is irrelevant, only within-bucket contiguity matters)
//   3. scatter pairs into stage via LDS-atomic rank
//   4. flush: thread t writes stage[t] to gbase[bkt] + (t - ofs[bkt]) --
//      consecutive threads hit consecutive global addresses within runs
//      of ~5-10 pairs, cutting 64B-line transactions ~8x vs scattered 8B.
// S side and D side processed sequentially, reusing the same stage.
// pairS = (ex, d | (s&127)<<17)  src-bucketed
// pairD = (ex, d&127)            dst-bucketed
// ---------------------------------------------------------------------------
#define PBT 512
#define EPT_P 8
#define PEB (PBT * EPT_P)  // 4096 edges per block
__global__ __launch_bounds__(PBT) void k_place(
    const int* __restrict__ src, const int* __restrict__ dst,
    const float* __restrict__ s1, const float* __restrict__ s2,
    int* __restrict__ sfill, int* __restrict__ dfill,
    float2* __restrict__ pairS, float2* __restrict__ pairD) {
  __shared__ int lc[NBKT];     // histogram, then rank counter
  __shared__ int ofs[NBKT];    // block-local stage offset
  __shared__ int gbase[NBKT];  // global target base (incl. bkt*CAP)
  __shared__ int tot;          // block-local stage allocator
  __shared__ float2 stage[PEB];
  __shared__ u16 stageB[PEB];  // bucket id per stage entry

  const int t = threadIdx.x;
  const int base = blockIdx.x * PEB + t;

  float ex[EPT_P];
  int pk[EPT_P];
  int bs[EPT_P];

  for (int i = t; i < NBKT; i += PBT) lc[i] = 0;
  if (t == 0) tot = 0;
  __syncthreads();

  // ---- compute + S-histogram ----
#pragma unroll
  for (int j = 0; j < EPT_P; j++) {
    int e = base + j * PBT;
    if (e < N_EDGES) {
      int s = src[e];
      int d = dst[e];
      float v = s1[s] + s2[d];
      v = v > 0.f ? v : LRELU_ALPHA * v;
      ex[j] = __expf(v);
      pk[j] = d | ((s & 127) << 17);
      bs[j] = s >> 7;
      atomicAdd(&lc[bs[j]], 1);
    } else {
      bs[j] = -1;
    }
  }
  __syncthreads();

  // ---- S: reserve global + local ranges ----
  for (int i = t; i < NBKT; i += PBT) {
    int c = lc[i];
    if (c) {
      gbase[i] = i * CAP + atomicAdd(&sfill[i], c);
      ofs[i] = atomicAdd(&tot, c);
    }
  }
  __syncthreads();
  const int nval = tot;  // # valid edges this block
  for (int i = t; i < NBKT; i += PBT) lc[i] = 0;
  __syncthreads();

  // ---- S: scatter to stage ----
#pragma unroll
  for (int j = 0; j < EPT_P; j++) {
    if (bs[j] >= 0) {
      int r = atomicAdd(&lc[bs[j]], 1);
      int idx = ofs[bs[j]] + r;
      stage[idx] = make_float2(ex[j], __int_as_float(pk[j]));
      stageB[idx] = (u16)bs[j];
    }
  }
  __syncthreads();

  // ---- S: coalesced flush ----
  for (int i = t; i < nval; i += PBT) {
    int bkt = stageB[i];
    pairS[gbase[bkt] + (i - ofs[bkt])] = stage[i];
  }
  __syncthreads();

  // ---- D: histogram ----
  for (int i = t; i < NBKT; i += PBT) lc[i] = 0;
  if (t == 0) tot = 0;
  __syncthreads();
#pragma unroll
  for (int j = 0; j < EPT_P; j++) {
    if (bs[j] >= 0) {
      int bd = (pk[j] & 0x1FFFF) >> 7;
      atomicAdd(&lc[bd], 1);
    }
  }
  __syncthreads();

  // ---- D: reserve ----
  for (int i = t; i < NBKT; i += PBT) {
    int c = lc[i];
    if (c) {
      gbase[i] = i * CAP + atomicAdd(&dfill[i], c);
      ofs[i] = atomicAdd(&tot, c);
    }
  }
  __syncthreads();
  for (int i = t; i < NBKT; i += PBT) lc[i] = 0;
  __syncthreads();

  // ---- D: scatter to stage ----
#pragma unroll
  for (int j = 0; j < EPT_P; j++) {
    if (bs[j] >= 0) {
      int d = pk[j] & 0x1FFFF;
      int bd = d >> 7;
      int r = atomicAdd(&lc[bd], 1);
      int idx = ofs[bd] + r;
      stage[idx] = make_float2(ex[j], __int_as_float(d & 127));
      stageB[idx] = (u16)bd;
    }
  }
  __syncthreads();

  // ---- D: coalesced flush ----
  for (int i = t; i < nval; i += PBT) {
    int bkt = stageB[i];
    pairD[gbase[bkt] + (i - ofs[bkt])] = stage[i];
  }
}

// ---------------------------------------------------------------------------
// denom: block per dst-bucket; LDS accumulate 128 sums; write RECIPROCAL.
// ---------------------------------------------------------------------------
__global__ __launch_bounds__(256) void k_denom(const int* __restrict__ dfill,
                                               const float2* __restrict__ pairD,
                                               float* __restrict__ denom_r) {
  __shared__ float lacc[128];
  const int t = threadIdx.x;
  const int bkt = blockIdx.x;
  if (t < 128) lacc[t] = 0.f;
  __syncthreads();
  int beg = bkt * CAP;
  int end = beg + dfill[bkt];
  for (int i = beg + t; i < end; i += 256) {
    float2 p = pairD[i];
    atomicAdd(&lacc[__float_as_int(p.y)], p.x);
  }
  __syncthreads();
  if (t < 128) {
    int node = bkt * 128 + t;
    if (node < N_NODES) denom_r[node] = 1.0f / lacc[t];
  }
}

// ---------------------------------------------------------------------------
// sort2: block per src-bucket. Exact node-sort within the bucket via LDS
// histogram + scan + LDS-atomic rank. Folds att = ex * 1/denom[d].
// Emits rowbe[node] = (beg,end) into padded pairA space.
// ---------------------------------------------------------------------------
__global__ __launch_bounds__(256) void k_sort2(
    const int* __restrict__ sfill, const float2* __restrict__ pairS,
    const float* __restrict__ denom_r, float2* __restrict__ pairA,
    int2* __restrict__ rowbe) {
  __shared__ int lcnt[128];
  __shared__ int cursor[128];
  __shared__ int w0tot;
  const int t = threadIdx.x;
  const int bkt = blockIdx.x;
  if (t < 128) lcnt[t] = 0;
  __syncthreads();

  const int beg = bkt * CAP;
  const int end = beg + sfill[bkt];

  for (int i = beg + t; i < end; i += 256) {
    int pkv = __float_as_int(pairS[i].y);
    atomicAdd(&lcnt[(pkv >> 17) & 127], 1);
  }
  __syncthreads();

  const int lane = t & 63;
  int v = (t < 128) ? lcnt[t] : 0;
  int val = v;
#pragma unroll
  for (int ofs = 1; ofs < 64; ofs <<= 1) {
    int u = __shfl_up(val, ofs, 64);
    if (lane >= ofs) val += u;
  }
  if (t == 63) w0tot = val;
  __syncthreads();
  int excl = val - v + ((t >= 64 && t < 128) ? w0tot : 0);
  if (t < 128) {
    cursor[t] = beg + excl;
    int node = bkt * 128 + t;
    if (node < N_NODES) rowbe[node] = make_int2(beg + excl, beg + excl + v);
  }
  __syncthreads();

  for (int i = beg + t; i < end; i += 256) {
    float2 p = pairS[i];
    int pkv = __float_as_int(p.y);
    int sl = (pkv >> 17) & 127;
    int d = pkv & 0x1FFFF;
    float att = p.x * denom_r[d];
    int pos = atomicAdd(&cursor[sl], 1);
    pairA[pos] = make_float2(att, __int_as_float(d));
  }
}

// ---------------------------------------------------------------------------
// aggregate: 4 nodes per wave (16 lanes/node, ushort4 = 4 features/lane).
// Each vmem instruction services 4 edges. Register acc, 2-wide unroll, elu.
// ---------------------------------------------------------------------------
__global__ __launch_bounds__(256) void k_aggregate(
    const int2* __restrict__ rowbe, const float2* __restrict__ pairA,
    const u16* __restrict__ hbf, float* __restrict__ out) {
  int wid = (blockIdx.x * 256 + threadIdx.x) >> 6;
  int lane = threadIdx.x & 63;
  int g = lane >> 4;
  int sl = lane & 15;
  int node = wid * 4 + g;
  int2 be = (node < N_NODES) ? rowbe[node] : make_int2(0, 0);
  float4 acc = make_float4(0.f, 0.f, 0.f, 0.f);
  int i = be.x;
  const int end = be.y;
  for (; i + 1 < end; i += 2) {
    float2 p0 = pairA[i];
    float2 p1 = pairA[i + 1];
    int d0 = __float_as_int(p0.y);
    int d1 = __float_as_int(p1.y);
    ushort4 q0 = *(const ushort4*)&hbf[(size_t)d0 * OUT_F + sl * 4];
    ushort4 q1 = *(const ushort4*)&hbf[(size_t)d1 * OUT_F + sl * 4];
    acc.x = fmaf(p0.x, bf2f(q0.x), acc.x);
    acc.y = fmaf(p0.x, bf2f(q0.y), acc.y);
    acc.z = fmaf(p0.x, bf2f(q0.z), acc.z);
    acc.w = fmaf(p0.x, bf2f(q0.w), acc.w);
    acc.x = fmaf(p1.x, bf2f(q1.x), acc.x);
    acc.y = fmaf(p1.x, bf2f(q1.y), acc.y);
    acc.z = fmaf(p1.x, bf2f(q1.z), acc.z);
    acc.w = fmaf(p1.x, bf2f(q1.w), acc.w);
  }
  if (i < end) {
    float2 p = pairA[i];
    int d = __float_as_int(p.y);
    ushort4 q = *(const ushort4*)&hbf[(size_t)d * OUT_F + sl * 4];
    acc.x = fmaf(p.x, bf2f(q.x), acc.x);
    acc.y = fmaf(p.x, bf2f(q.y), acc.y);
    acc.z = fmaf(p.x, bf2f(q.z), acc.z);
    acc.w = fmaf(p.x, bf2f(q.w), acc.w);
  }
  if (node < N_NODES) {
    float4 o;
    o.x = acc.x > 0.f ? acc.x : expm1f(acc.x);
    o.y = acc.y > 0.f ? acc.y : expm1f(acc.y);
    o.z = acc.z > 0.f ? acc.z : expm1f(acc.z);
    o.w = acc.w > 0.f ? acc.w : expm1f(acc.w);
    *(float4*)(out + (size_t)node * OUT_F + sl * 4) = o;
  }
}

// ---------------------------------------------------------------------------
extern "C" void kernel_launch(void* const* d_in, const int* in_sizes, int n_in,
                              void* d_out, int out_size, void* d_ws,
                              size_t ws_size, hipStream_t stream) {
  const int* adj = (const int*)d_in[0];
  const float* x = (const float*)d_in[1];
  const float* W = (const float*)d_in[2];
  const float* b = (const float*)d_in[3];
  const float* a = (const float*)d_in[4];
  float* out = (float*)d_out;

  float* ws = (float*)d_ws;
  float* s1v = ws;                            // 100,000
  float* s2v = ws + 100000;                   // 100,000
  float* denom_r = ws + 200000;               // 100,000
  int* sfill = (int*)(ws + 300000);           // 782 (pad 800)
  int* dfill = (int*)(ws + 300800);           // 782 (pad 800)
  int2* rowbe = (int2*)(ws + 301600);         // 100,000 int2 = 200,000 f
  float2* pairS = (float2*)(ws + 501600);     // 782*4480 float2 = 7,006,720 f
  float2* pairD = (float2*)(ws + 7508320);    // 782*4480 float2 (reused: pairA)
  u16* hbf = (u16*)(ws + 14515040);           // 6.4M u16 = 3.2M f
  u16* Wbf = (u16*)(ws + 17715040);           // 16,384 u16
  // total ~17.73M floats = 70.9 MB

  float2* pairA = pairD;  // denom consumes pairD before sort2 overwrites

  const int* src = adj;
  const int* dst = adj + N_EDGES;

  k_prep<<<65, 256, 0, stream>>>(W, Wbf, sfill, dfill);
  k_linear<<<(N_NODES + 63) / 64, 256, 0, stream>>>(x, Wbf, b, a, hbf, s1v, s2v);
  k_place<<<(N_EDGES + PEB - 1) / PEB, PBT, 0, stream>>>(
      src, dst, s1v, s2v, sfill, dfill, pairS, pairD);
  k_denom<<<NBKT, 256, 0, stream>>>(dfill, pairD, denom_r);
  k_sort2<<<NBKT, 256, 0, stream>>>(sfill, pairS, denom_r, pairA, rowbe);
  k_aggregate<<<(N_NODES + 15) / 16, 256, 0, stream>>>(rowbe, pairA, hbf, out);
}

// Round 4
// 369.906 us; speedup vs baseline: 1.3414x; 1.1081x over previous
//
#include <hip/hip_runtime.h>
#include <math.h>

#define N_NODES 100000
#define N_EDGES 3200000
#define IN_F 256
#define OUT_F 64
#define LRELU_ALPHA 0.2f
#define NBKT 782   // ceil(100000/128) coarse buckets of 128 nodes
#define CAP 4480   // bucket capacity: mean 4096 + 6 sigma (sigma=64)

typedef unsigned short u16;
typedef __attribute__((ext_vector_type(8))) short short8;
typedef __attribute__((ext_vector_type(4))) float floatx4;

__device__ inline u16 f2bf(float f) {  // RNE fp32 -> bf16
  unsigned u = __float_as_uint(f);
  u += 0x7FFFu + ((u >> 16) & 1u);
  return (u16)(u >> 16);
}
__device__ inline float bf2f(u16 h) {
  return __uint_as_float(((unsigned)h) << 16);
}

// ---------------------------------------------------------------------------
// prep: blocks 0..63 convert W to bf16; block 64 zeros the bucket fill ctrs
// ---------------------------------------------------------------------------
__global__ __launch_bounds__(256) void k_prep(const float* __restrict__ W,
                                              u16* __restrict__ Wbf,
                                              int* __restrict__ sfill,
                                              int* __restrict__ dfill) {
  if (blockIdx.x < 64) {
    int i = blockIdx.x * 256 + threadIdx.x;
    Wbf[i] = f2bf(W[i]);
  } else {
    for (int i = threadIdx.x; i < NBKT; i += 256) {
      sfill[i] = 0;
      dfill[i] = 0;
    }
  }
}

// ---------------------------------------------------------------------------
// linear via bf16 MFMA: h = x@W^T + b (stored bf16); s1 = h.a1; s2 = h.a2
// ---------------------------------------------------------------------------
__global__ __launch_bounds__(256) void k_linear(
    const float* __restrict__ x, const u16* __restrict__ Wbf,
    const float* __restrict__ b, const float* __restrict__ a,
    u16* __restrict__ hbf, float* __restrict__ s1, float* __restrict__ s2) {
  __shared__ u16 Wlds[64 * 264];

  const int t = threadIdx.x;
#pragma unroll
  for (int p = 0; p < 8; p++) {
    int c = p * 256 + t;
    int row = c >> 5;
    int kc = (c & 31) * 8;
    *(short8*)&Wlds[row * 264 + kc] = *(const short8*)&Wbf[row * 256 + kc];
  }
  __syncthreads();

  const int w = t >> 6;
  const int lane = t & 63;
  const int col = lane & 15;
  const int q = lane >> 4;
  const int m0 = blockIdx.x * 64 + w * 16;

  floatx4 acc[4];
#pragma unroll
  for (int nt = 0; nt < 4; nt++) acc[nt] = (floatx4){0.f, 0.f, 0.f, 0.f};

  int mrow = m0 + col;
  if (mrow > N_NODES - 1) mrow = N_NODES - 1;
  const float* xrow = x + (size_t)mrow * IN_F + q * 8;

#pragma unroll
  for (int kk = 0; kk < 8; kk++) {
    float4 f0 = *(const float4*)(xrow + kk * 32);
    float4 f1 = *(const float4*)(xrow + kk * 32 + 4);
    short8 af;
    af[0] = (short)f2bf(f0.x);
    af[1] = (short)f2bf(f0.y);
    af[2] = (short)f2bf(f0.z);
    af[3] = (short)f2bf(f0.w);
    af[4] = (short)f2bf(f1.x);
    af[5] = (short)f2bf(f1.y);
    af[6] = (short)f2bf(f1.z);
    af[7] = (short)f2bf(f1.w);
#pragma unroll
    for (int nt = 0; nt < 4; nt++) {
      short8 bfr = *(const short8*)&Wlds[(nt * 16 + col) * 264 + kk * 32 + q * 8];
      acc[nt] = __builtin_amdgcn_mfma_f32_16x16x32_bf16(af, bfr, acc[nt], 0, 0, 0);
    }
  }

  float bv[4], a1v[4], a2v[4];
#pragma unroll
  for (int nt = 0; nt < 4; nt++) {
    bv[nt] = b[nt * 16 + col];
    a1v[nt] = a[nt * 16 + col];
    a2v[nt] = a[OUT_F + nt * 16 + col];
  }
#pragma unroll
  for (int r = 0; r < 4; r++) {
    int node = m0 + q * 4 + r;
    float p1 = 0.f, p2 = 0.f;
#pragma unroll
    for (int nt = 0; nt < 4; nt++) {
      float hv = acc[nt][r] + bv[nt];
      if (node < N_NODES) hbf[(size_t)node * OUT_F + nt * 16 + col] = f2bf(hv);
      p1 = fmaf(hv, a1v[nt], p1);
      p2 = fmaf(hv, a2v[nt], p2);
    }
#pragma unroll
    for (int s = 1; s < 16; s <<= 1) {
      p1 += __shfl_xor(p1, s, 16);
      p2 += __shfl_xor(p2, s, 16);
    }
    if (col == 0 && node < N_NODES) {
      s1[node] = p1;
      s2[node] = p2;
    }
  }
}

// ---------------------------------------------------------------------------
// place: ex = exp(leakyrelu(s1[src]+s2[dst])); write into PADDED buckets
// (bucket b occupies [b*CAP, b*CAP + fill[b])). Block-local LDS staging +
// coalesced flush (verified R3: WRITE_SIZE 145->80 MB).
// pairS = (ex, d | (s&127)<<17)  src-bucketed
// pairD = (ex, d&127)            dst-bucketed
// ---------------------------------------------------------------------------
#define PBT 512
#define EPT_P 8
#define PEB (PBT * EPT_P)  // 4096 edges per block
__global__ __launch_bounds__(PBT) void k_place(
    const int* __restrict__ src, const int* __restrict__ dst,
    const float* __restrict__ s1, const float* __restrict__ s2,
    int* __restrict__ sfill, int* __restrict__ dfill,
    float2* __restrict__ pairS, float2* __restrict__ pairD) {
  __shared__ int lc[NBKT];     // histogram, then rank counter
  __shared__ int ofs[NBKT];    // block-local stage offset
  __shared__ int gbase[NBKT];  // global target base (incl. bkt*CAP)
  __shared__ int tot;          // block-local stage allocator
  __shared__ float2 stage[PEB];
  __shared__ u16 stageB[PEB];  // bucket id per stage entry

  const int t = threadIdx.x;
  const int base = blockIdx.x * PEB + t;

  float ex[EPT_P];
  int pk[EPT_P];
  int bs[EPT_P];

  for (int i = t; i < NBKT; i += PBT) lc[i] = 0;
  if (t == 0) tot = 0;
  __syncthreads();

  // ---- compute + S-histogram ----
#pragma unroll
  for (int j = 0; j < EPT_P; j++) {
    int e = base + j * PBT;
    if (e < N_EDGES) {
      int s = src[e];
      int d = dst[e];
      float v = s1[s] + s2[d];
      v = v > 0.f ? v : LRELU_ALPHA * v;
      ex[j] = __expf(v);
      pk[j] = d | ((s & 127) << 17);
      bs[j] = s >> 7;
      atomicAdd(&lc[bs[j]], 1);
    } else {
      bs[j] = -1;
    }
  }
  __syncthreads();

  // ---- S: reserve global + local ranges ----
  for (int i = t; i < NBKT; i += PBT) {
    int c = lc[i];
    if (c) {
      gbase[i] = i * CAP + atomicAdd(&sfill[i], c);
      ofs[i] = atomicAdd(&tot, c);
    }
  }
  __syncthreads();
  const int nval = tot;  // # valid edges this block
  for (int i = t; i < NBKT; i += PBT) lc[i] = 0;
  __syncthreads();

  // ---- S: scatter to stage ----
#pragma unroll
  for (int j = 0; j < EPT_P; j++) {
    if (bs[j] >= 0) {
      int r = atomicAdd(&lc[bs[j]], 1);
      int idx = ofs[bs[j]] + r;
      stage[idx] = make_float2(ex[j], __int_as_float(pk[j]));
      stageB[idx] = (u16)bs[j];
    }
  }
  __syncthreads();

  // ---- S: coalesced flush ----
  for (int i = t; i < nval; i += PBT) {
    int bkt = stageB[i];
    pairS[gbase[bkt] + (i - ofs[bkt])] = stage[i];
  }
  __syncthreads();

  // ---- D: histogram ----
  for (int i = t; i < NBKT; i += PBT) lc[i] = 0;
  if (t == 0) tot = 0;
  __syncthreads();
#pragma unroll
  for (int j = 0; j < EPT_P; j++) {
    if (bs[j] >= 0) {
      int bd = (pk[j] & 0x1FFFF) >> 7;
      atomicAdd(&lc[bd], 1);
    }
  }
  __syncthreads();

  // ---- D: reserve ----
  for (int i = t; i < NBKT; i += PBT) {
    int c = lc[i];
    if (c) {
      gbase[i] = i * CAP + atomicAdd(&dfill[i], c);
      ofs[i] = atomicAdd(&tot, c);
    }
  }
  __syncthreads();
  for (int i = t; i < NBKT; i += PBT) lc[i] = 0;
  __syncthreads();

  // ---- D: scatter to stage ----
#pragma unroll
  for (int j = 0; j < EPT_P; j++) {
    if (bs[j] >= 0) {
      int d = pk[j] & 0x1FFFF;
      int bd = d >> 7;
      int r = atomicAdd(&lc[bd], 1);
      int idx = ofs[bd] + r;
      stage[idx] = make_float2(ex[j], __int_as_float(d & 127));
      stageB[idx] = (u16)bd;
    }
  }
  __syncthreads();

  // ---- D: coalesced flush ----
  for (int i = t; i < nval; i += PBT) {
    int bkt = stageB[i];
    pairD[gbase[bkt] + (i - ofs[bkt])] = stage[i];
  }
}

// ---------------------------------------------------------------------------
// denom: block per dst-bucket; LDS accumulate 128 sums; write RECIPROCAL.
// ---------------------------------------------------------------------------
__global__ __launch_bounds__(256) void k_denom(const int* __restrict__ dfill,
                                               const float2* __restrict__ pairD,
                                               float* __restrict__ denom_r) {
  __shared__ float lacc[128];
  const int t = threadIdx.x;
  const int bkt = blockIdx.x;
  if (t < 128) lacc[t] = 0.f;
  __syncthreads();
  int beg = bkt * CAP;
  int end = beg + dfill[bkt];
  for (int i = beg + t; i < end; i += 256) {
    float2 p = pairD[i];
    atomicAdd(&lacc[__float_as_int(p.y)], p.x);
  }
  __syncthreads();
  if (t < 128) {
    int node = bkt * 128 + t;
    if (node < N_NODES) denom_r[node] = 1.0f / lacc[t];
  }
}

// ---------------------------------------------------------------------------
// sortagg: FUSED sort2 + aggregate. Block (512 thr) per src-bucket.
//  1. LDS histogram of node-slot (s&127) + scan -> per-node [beg,end) in a
//     bucket-local LDS stage (<= CAP entries, 35.8 KB)
//  2. scatter att-folded pairs (att = ex * denom_r[d]) into LDS stage at
//     sorted positions (LDS atomic rank) -- NO global pairA round trip
//  3. aggregate from LDS: 16 lanes/node, float4 register acc, gather
//     hbf[d] rows (coalesced 128B), ELU, coalesced out write.
// Eliminates pairA write+read (~51 MB, scatter-amplified) + rowbe + 1 launch.
// ---------------------------------------------------------------------------
#define SAT 512
__global__ __launch_bounds__(SAT) void k_sortagg(
    const int* __restrict__ sfill, const float2* __restrict__ pairS,
    const float* __restrict__ denom_r, const u16* __restrict__ hbf,
    float* __restrict__ out) {
  __shared__ float2 stg[CAP];
  __shared__ int lcnt[128];
  __shared__ int cur[128];
  __shared__ int nbeg[128];
  __shared__ int nend[128];
  __shared__ int w0tot;
  const int t = threadIdx.x;
  const int bkt = blockIdx.x;

  if (t < 128) lcnt[t] = 0;
  __syncthreads();

  const int gbeg = bkt * CAP;
  const int ne = sfill[bkt];

  // ---- histogram ----
  for (int i = t; i < ne; i += SAT) {
    int pkv = __float_as_int(pairS[gbeg + i].y);
    atomicAdd(&lcnt[(pkv >> 17) & 127], 1);
  }
  __syncthreads();

  // ---- scan (128 entries over 2 waves) ----
  const int lane = t & 63;
  int v = (t < 128) ? lcnt[t] : 0;
  int val = v;
#pragma unroll
  for (int o = 1; o < 64; o <<= 1) {
    int u = __shfl_up(val, o, 64);
    if (lane >= o) val += u;
  }
  if (t == 63) w0tot = val;
  __syncthreads();
  if (t < 128) {
    int excl = val - v + ((t >= 64) ? w0tot : 0);
    cur[t] = excl;
    nbeg[t] = excl;
    nend[t] = excl + v;
  }
  __syncthreads();

  // ---- scatter into LDS stage with att folded ----
  for (int i = t; i < ne; i += SAT) {
    float2 p = pairS[gbeg + i];
    int pkv = __float_as_int(p.y);
    int sl = (pkv >> 17) & 127;
    int d = pkv & 0x1FFFF;
    float att = p.x * denom_r[d];
    int pos = atomicAdd(&cur[sl], 1);
    stg[pos] = make_float2(att, __int_as_float(d));
  }
  __syncthreads();

  // ---- aggregate: 32 groups of 16 lanes; each group 4 nodes ----
  const int G = t >> 4;   // 0..31
  const int sl = t & 15;  // feature quad
  for (int nl = G; nl < 128; nl += 32) {
    int node = bkt * 128 + nl;
    int i = nbeg[nl];
    const int e0 = nend[nl];
    float4 acc = make_float4(0.f, 0.f, 0.f, 0.f);
    for (; i + 1 < e0; i += 2) {
      float2 p0 = stg[i];
      float2 p1 = stg[i + 1];
      int d0 = __float_as_int(p0.y);
      int d1 = __float_as_int(p1.y);
      ushort4 q0 = *(const ushort4*)&hbf[(size_t)d0 * OUT_F + sl * 4];
      ushort4 q1 = *(const ushort4*)&hbf[(size_t)d1 * OUT_F + sl * 4];
      acc.x = fmaf(p0.x, bf2f(q0.x), acc.x);
      acc.y = fmaf(p0.x, bf2f(q0.y), acc.y);
      acc.z = fmaf(p0.x, bf2f(q0.z), acc.z);
      acc.w = fmaf(p0.x, bf2f(q0.w), acc.w);
      acc.x = fmaf(p1.x, bf2f(q1.x), acc.x);
      acc.y = fmaf(p1.x, bf2f(q1.y), acc.y);
      acc.z = fmaf(p1.x, bf2f(q1.z), acc.z);
      acc.w = fmaf(p1.x, bf2f(q1.w), acc.w);
    }
    if (i < e0) {
      float2 p = stg[i];
      int d = __float_as_int(p.y);
      ushort4 q = *(const ushort4*)&hbf[(size_t)d * OUT_F + sl * 4];
      acc.x = fmaf(p.x, bf2f(q.x), acc.x);
      acc.y = fmaf(p.x, bf2f(q.y), acc.y);
      acc.z = fmaf(p.x, bf2f(q.z), acc.z);
      acc.w = fmaf(p.x, bf2f(q.w), acc.w);
    }
    if (node < N_NODES) {
      float4 o;
      o.x = acc.x > 0.f ? acc.x : expm1f(acc.x);
      o.y = acc.y > 0.f ? acc.y : expm1f(acc.y);
      o.z = acc.z > 0.f ? acc.z : expm1f(acc.z);
      o.w = acc.w > 0.f ? acc.w : expm1f(acc.w);
      *(float4*)(out + (size_t)node * OUT_F + sl * 4) = o;
    }
  }
}

// ---------------------------------------------------------------------------
extern "C" void kernel_launch(void* const* d_in, const int* in_sizes, int n_in,
                              void* d_out, int out_size, void* d_ws,
                              size_t ws_size, hipStream_t stream) {
  const int* adj = (const int*)d_in[0];
  const float* x = (const float*)d_in[1];
  const float* W = (const float*)d_in[2];
  const float* b = (const float*)d_in[3];
  const float* a = (const float*)d_in[4];
  float* out = (float*)d_out;

  float* ws = (float*)d_ws;
  float* s1v = ws;                            // 100,000
  float* s2v = ws + 100000;                   // 100,000
  float* denom_r = ws + 200000;               // 100,000
  int* sfill = (int*)(ws + 300000);           // 782 (pad 800)
  int* dfill = (int*)(ws + 300800);           // 782 (pad 800)
  float2* pairS = (float2*)(ws + 301600);     // 782*4480 float2 = 7,006,720 f
  float2* pairD = (float2*)(ws + 7308320);    // 782*4480 float2
  u16* hbf = (u16*)(ws + 14315040);           // 6.4M u16 = 3.2M f
  u16* Wbf = (u16*)(ws + 17515040);           // 16,384 u16
  // total ~17.52M floats = 70.1 MB

  const int* src = adj;
  const int* dst = adj + N_EDGES;

  k_prep<<<65, 256, 0, stream>>>(W, Wbf, sfill, dfill);
  k_linear<<<(N_NODES + 63) / 64, 256, 0, stream>>>(x, Wbf, b, a, hbf, s1v, s2v);
  k_place<<<(N_EDGES + PEB - 1) / PEB, PBT, 0, stream>>>(
      src, dst, s1v, s2v, sfill, dfill, pairS, pairD);
  k_denom<<<NBKT, 256, 0, stream>>>(dfill, pairD, denom_r);
  k_sortagg<<<NBKT, SAT, 0, stream>>>(sfill, pairS, denom_r, hbf, out);
}

// Round 5
// 365.469 us; speedup vs baseline: 1.3577x; 1.0121x over previous
//
#include <hip/hip_runtime.h>
#include <math.h>

#define N_NODES 100000
#define N_EDGES 3200000
#define IN_F 256
#define OUT_F 64
#define LRELU_ALPHA 0.2f
#define NBKT 782   // ceil(100000/128) coarse buckets of 128 nodes
#define CAP 4480   // bucket capacity: mean 4096 + 6 sigma (sigma=64)

typedef unsigned short u16;
typedef __attribute__((ext_vector_type(8))) short short8;
typedef __attribute__((ext_vector_type(4))) float floatx4;

__device__ inline u16 f2bf(float f) {  // RNE fp32 -> bf16
  unsigned u = __float_as_uint(f);
  u += 0x7FFFu + ((u >> 16) & 1u);
  return (u16)(u >> 16);
}
__device__ inline float bf2f(u16 h) {
  return __uint_as_float(((unsigned)h) << 16);
}

// ---------------------------------------------------------------------------
// prep: blocks 0..63 convert W to bf16; block 64 zeros the bucket fill ctrs
// ---------------------------------------------------------------------------
__global__ __launch_bounds__(256) void k_prep(const float* __restrict__ W,
                                              u16* __restrict__ Wbf,
                                              int* __restrict__ sfill,
                                              int* __restrict__ dfill) {
  if (blockIdx.x < 64) {
    int i = blockIdx.x * 256 + threadIdx.x;
    Wbf[i] = f2bf(W[i]);
  } else {
    for (int i = threadIdx.x; i < NBKT; i += 256) {
      sfill[i] = 0;
      dfill[i] = 0;
    }
  }
}

// ---------------------------------------------------------------------------
// linear via bf16 MFMA: h = x@W^T + b (stored bf16); s1 = h.a1; s2 = h.a2
// ---------------------------------------------------------------------------
__global__ __launch_bounds__(256) void k_linear(
    const float* __restrict__ x, const u16* __restrict__ Wbf,
    const float* __restrict__ b, const float* __restrict__ a,
    u16* __restrict__ hbf, float* __restrict__ s1, float* __restrict__ s2) {
  __shared__ u16 Wlds[64 * 264];

  const int t = threadIdx.x;
#pragma unroll
  for (int p = 0; p < 8; p++) {
    int c = p * 256 + t;
    int row = c >> 5;
    int kc = (c & 31) * 8;
    *(short8*)&Wlds[row * 264 + kc] = *(const short8*)&Wbf[row * 256 + kc];
  }
  __syncthreads();

  const int w = t >> 6;
  const int lane = t & 63;
  const int col = lane & 15;
  const int q = lane >> 4;
  const int m0 = blockIdx.x * 64 + w * 16;

  floatx4 acc[4];
#pragma unroll
  for (int nt = 0; nt < 4; nt++) acc[nt] = (floatx4){0.f, 0.f, 0.f, 0.f};

  int mrow = m0 + col;
  if (mrow > N_NODES - 1) mrow = N_NODES - 1;
  const float* xrow = x + (size_t)mrow * IN_F + q * 8;

#pragma unroll
  for (int kk = 0; kk < 8; kk++) {
    float4 f0 = *(const float4*)(xrow + kk * 32);
    float4 f1 = *(const float4*)(xrow + kk * 32 + 4);
    short8 af;
    af[0] = (short)f2bf(f0.x);
    af[1] = (short)f2bf(f0.y);
    af[2] = (short)f2bf(f0.z);
    af[3] = (short)f2bf(f0.w);
    af[4] = (short)f2bf(f1.x);
    af[5] = (short)f2bf(f1.y);
    af[6] = (short)f2bf(f1.z);
    af[7] = (short)f2bf(f1.w);
#pragma unroll
    for (int nt = 0; nt < 4; nt++) {
      short8 bfr = *(const short8*)&Wlds[(nt * 16 + col) * 264 + kk * 32 + q * 8];
      acc[nt] = __builtin_amdgcn_mfma_f32_16x16x32_bf16(af, bfr, acc[nt], 0, 0, 0);
    }
  }

  float bv[4], a1v[4], a2v[4];
#pragma unroll
  for (int nt = 0; nt < 4; nt++) {
    bv[nt] = b[nt * 16 + col];
    a1v[nt] = a[nt * 16 + col];
    a2v[nt] = a[OUT_F + nt * 16 + col];
  }
#pragma unroll
  for (int r = 0; r < 4; r++) {
    int node = m0 + q * 4 + r;
    float p1 = 0.f, p2 = 0.f;
#pragma unroll
    for (int nt = 0; nt < 4; nt++) {
      float hv = acc[nt][r] + bv[nt];
      if (node < N_NODES) hbf[(size_t)node * OUT_F + nt * 16 + col] = f2bf(hv);
      p1 = fmaf(hv, a1v[nt], p1);
      p2 = fmaf(hv, a2v[nt], p2);
    }
#pragma unroll
    for (int s = 1; s < 16; s <<= 1) {
      p1 += __shfl_xor(p1, s, 16);
      p2 += __shfl_xor(p2, s, 16);
    }
    if (col == 0 && node < N_NODES) {
      s1[node] = p1;
      s2[node] = p2;
    }
  }
}

// ---------------------------------------------------------------------------
// place: ex = exp(leakyrelu(s1[src]+s2[dst])); write into PADDED buckets.
// R5: S-side and D-side are now INDEPENDENT blocks (blockIdx.y = 0/1) --
// halves the per-block barrier chain and doubles resident parallelism.
// Both sides recompute ex (cheap: VALU was 12% busy; s1/s2 L2-resident).
// Block-local LDS staging + coalesced flush (verified: WRITE 145->80 MB).
// pairS = float2 (ex, d | (s&127)<<17)  src-bucketed
// pairD = u32 (bf16(ex)<<16 | d&127)    dst-bucketed, 4 B/edge
// ---------------------------------------------------------------------------
#define PBT 512
#define EPT_P 8
#define PEB (PBT * EPT_P)  // 4096 edges per block
__global__ __launch_bounds__(PBT) void k_place(
    const int* __restrict__ src, const int* __restrict__ dst,
    const float* __restrict__ s1, const float* __restrict__ s2,
    int* __restrict__ sfill, int* __restrict__ dfill,
    float2* __restrict__ pairS, unsigned* __restrict__ pairD) {
  __shared__ int lc[NBKT];     // histogram, then rank counter
  __shared__ int ofs[NBKT];    // block-local stage offset
  __shared__ int gbase[NBKT];  // global target base (incl. bkt*CAP)
  __shared__ int tot;          // block-local stage allocator
  __shared__ float2 stage[PEB];
  __shared__ u16 stageB[PEB];  // bucket id per stage entry

  const int t = threadIdx.x;
  const int side = blockIdx.y;  // 0 = S (src-bucket), 1 = D (dst-bucket)
  const int base = blockIdx.x * PEB + t;

  float ex[EPT_P];
  int key[EPT_P];
  int bk[EPT_P];

  for (int i = t; i < NBKT; i += PBT) lc[i] = 0;
  if (t == 0) tot = 0;
  __syncthreads();

  // ---- compute + histogram (side-specific bucket) ----
#pragma unroll
  for (int j = 0; j < EPT_P; j++) {
    int e = base + j * PBT;
    if (e < N_EDGES) {
      int s = src[e];
      int d = dst[e];
      float v = s1[s] + s2[d];
      v = v > 0.f ? v : LRELU_ALPHA * v;
      ex[j] = __expf(v);
      if (side == 0) {
        key[j] = d | ((s & 127) << 17);
        bk[j] = s >> 7;
      } else {
        key[j] = d & 127;
        bk[j] = d >> 7;
      }
      atomicAdd(&lc[bk[j]], 1);
    } else {
      bk[j] = -1;
    }
  }
  __syncthreads();

  // ---- reserve global + local ranges ----
  int* fill = side ? dfill : sfill;
  for (int i = t; i < NBKT; i += PBT) {
    int c = lc[i];
    if (c) {
      gbase[i] = i * CAP + atomicAdd(&fill[i], c);
      ofs[i] = atomicAdd(&tot, c);
    }
  }
  __syncthreads();
  const int nval = tot;  // # valid edges this block
  for (int i = t; i < NBKT; i += PBT) lc[i] = 0;
  __syncthreads();

  if (side == 0) {
    // ---- S: scatter to stage ----
#pragma unroll
    for (int j = 0; j < EPT_P; j++) {
      if (bk[j] >= 0) {
        int r = atomicAdd(&lc[bk[j]], 1);
        int idx = ofs[bk[j]] + r;
        stage[idx] = make_float2(ex[j], __int_as_float(key[j]));
        stageB[idx] = (u16)bk[j];
      }
    }
    __syncthreads();
    // ---- S: coalesced flush ----
    for (int i = t; i < nval; i += PBT) {
      int bkt = stageB[i];
      pairS[gbase[bkt] + (i - ofs[bkt])] = stage[i];
    }
  } else {
    // ---- D: scatter to stage (packed u32) ----
    unsigned* stg32 = (unsigned*)stage;
#pragma unroll
    for (int j = 0; j < EPT_P; j++) {
      if (bk[j] >= 0) {
        int r = atomicAdd(&lc[bk[j]], 1);
        int idx = ofs[bk[j]] + r;
        stg32[idx] = ((unsigned)f2bf(ex[j]) << 16) | (unsigned)key[j];
        stageB[idx] = (u16)bk[j];
      }
    }
    __syncthreads();
    // ---- D: coalesced flush ----
    for (int i = t; i < nval; i += PBT) {
      int bkt = stageB[i];
      pairD[gbase[bkt] + (i - ofs[bkt])] = stg32[i];
    }
  }
}

// ---------------------------------------------------------------------------
// denom: block per dst-bucket; LDS accumulate 128 sums; write RECIPROCAL.
// pairD entries are 4B: (bf16 ex << 16) | slot7. Masking low 16 bits gives
// the bf16 value as fp32 directly.
// ---------------------------------------------------------------------------
__global__ __launch_bounds__(256) void k_denom(const int* __restrict__ dfill,
                                               const unsigned* __restrict__ pairD,
                                               float* __restrict__ denom_r) {
  __shared__ float lacc[128];
  const int t = threadIdx.x;
  const int bkt = blockIdx.x;
  if (t < 128) lacc[t] = 0.f;
  __syncthreads();
  int beg = bkt * CAP;
  int end = beg + dfill[bkt];
  for (int i = beg + t; i < end; i += 256) {
    unsigned u = pairD[i];
    atomicAdd(&lacc[u & 127], __uint_as_float(u & 0xFFFF0000u));
  }
  __syncthreads();
  if (t < 128) {
    int node = bkt * 128 + t;
    if (node < N_NODES) denom_r[node] = 1.0f / lacc[t];
  }
}

// ---------------------------------------------------------------------------
// sortagg: FUSED sort2 + aggregate. Block (512 thr) per src-bucket.
//  1. LDS histogram of node-slot (s&127) + scan -> per-node [beg,end) in a
//     bucket-local LDS stage (<= CAP entries, 35.8 KB)
//  2. scatter att-folded pairs (att = ex * denom_r[d]) into LDS stage at
//     sorted positions (LDS atomic rank) -- NO global pairA round trip
//  3. aggregate from LDS: 16 lanes/node, float4 register acc, gather
//     hbf[d] rows (coalesced 128B), ELU, coalesced out write.
// ---------------------------------------------------------------------------
#define SAT 512
__global__ __launch_bounds__(SAT) void k_sortagg(
    const int* __restrict__ sfill, const float2* __restrict__ pairS,
    const float* __restrict__ denom_r, const u16* __restrict__ hbf,
    float* __restrict__ out) {
  __shared__ float2 stg[CAP];
  __shared__ int lcnt[128];
  __shared__ int cur[128];
  __shared__ int nbeg[128];
  __shared__ int nend[128];
  __shared__ int w0tot;
  const int t = threadIdx.x;
  const int bkt = blockIdx.x;

  if (t < 128) lcnt[t] = 0;
  __syncthreads();

  const int gbeg = bkt * CAP;
  const int ne = sfill[bkt];

  // ---- histogram ----
  for (int i = t; i < ne; i += SAT) {
    int pkv = __float_as_int(pairS[gbeg + i].y);
    atomicAdd(&lcnt[(pkv >> 17) & 127], 1);
  }
  __syncthreads();

  // ---- scan (128 entries over 2 waves) ----
  const int lane = t & 63;
  int v = (t < 128) ? lcnt[t] : 0;
  int val = v;
#pragma unroll
  for (int o = 1; o < 64; o <<= 1) {
    int u = __shfl_up(val, o, 64);
    if (lane >= o) val += u;
  }
  if (t == 63) w0tot = val;
  __syncthreads();
  if (t < 128) {
    int excl = val - v + ((t >= 64) ? w0tot : 0);
    cur[t] = excl;
    nbeg[t] = excl;
    nend[t] = excl + v;
  }
  __syncthreads();

  // ---- scatter into LDS stage with att folded ----
  for (int i = t; i < ne; i += SAT) {
    float2 p = pairS[gbeg + i];
    int pkv = __float_as_int(p.y);
    int sl = (pkv >> 17) & 127;
    int d = pkv & 0x1FFFF;
    float att = p.x * denom_r[d];
    int pos = atomicAdd(&cur[sl], 1);
    stg[pos] = make_float2(att, __int_as_float(d));
  }
  __syncthreads();

  // ---- aggregate: 32 groups of 16 lanes; each group 4 nodes ----
  const int G = t >> 4;   // 0..31
  const int sl = t & 15;  // feature quad
  for (int nl = G; nl < 128; nl += 32) {
    int node = bkt * 128 + nl;
    int i = nbeg[nl];
    const int e0 = nend[nl];
    float4 acc = make_float4(0.f, 0.f, 0.f, 0.f);
    for (; i + 1 < e0; i += 2) {
      float2 p0 = stg[i];
      float2 p1 = stg[i + 1];
      int d0 = __float_as_int(p0.y);
      int d1 = __float_as_int(p1.y);
      ushort4 q0 = *(const ushort4*)&hbf[(size_t)d0 * OUT_F + sl * 4];
      ushort4 q1 = *(const ushort4*)&hbf[(size_t)d1 * OUT_F + sl * 4];
      acc.x = fmaf(p0.x, bf2f(q0.x), acc.x);
      acc.y = fmaf(p0.x, bf2f(q0.y), acc.y);
      acc.z = fmaf(p0.x, bf2f(q0.z), acc.z);
      acc.w = fmaf(p0.x, bf2f(q0.w), acc.w);
      acc.x = fmaf(p1.x, bf2f(q1.x), acc.x);
      acc.y = fmaf(p1.x, bf2f(q1.y), acc.y);
      acc.z = fmaf(p1.x, bf2f(q1.z), acc.z);
      acc.w = fmaf(p1.x, bf2f(q1.w), acc.w);
    }
    if (i < e0) {
      float2 p = stg[i];
      int d = __float_as_int(p.y);
      ushort4 q = *(const ushort4*)&hbf[(size_t)d * OUT_F + sl * 4];
      acc.x = fmaf(p.x, bf2f(q.x), acc.x);
      acc.y = fmaf(p.x, bf2f(q.y), acc.y);
      acc.z = fmaf(p.x, bf2f(q.z), acc.z);
      acc.w = fmaf(p.x, bf2f(q.w), acc.w);
    }
    if (node < N_NODES) {
      float4 o;
      o.x = acc.x > 0.f ? acc.x : expm1f(acc.x);
      o.y = acc.y > 0.f ? acc.y : expm1f(acc.y);
      o.z = acc.z > 0.f ? acc.z : expm1f(acc.z);
      o.w = acc.w > 0.f ? acc.w : expm1f(acc.w);
      *(float4*)(out + (size_t)node * OUT_F + sl * 4) = o;
    }
  }
}

// ---------------------------------------------------------------------------
extern "C" void kernel_launch(void* const* d_in, const int* in_sizes, int n_in,
                              void* d_out, int out_size, void* d_ws,
                              size_t ws_size, hipStream_t stream) {
  const int* adj = (const int*)d_in[0];
  const float* x = (const float*)d_in[1];
  const float* W = (const float*)d_in[2];
  const float* b = (const float*)d_in[3];
  const float* a = (const float*)d_in[4];
  float* out = (float*)d_out;

  float* ws = (float*)d_ws;
  float* s1v = ws;                            // 100,000
  float* s2v = ws + 100000;                   // 100,000
  float* denom_r = ws + 200000;               // 100,000
  int* sfill = (int*)(ws + 300000);           // 782 (pad 800)
  int* dfill = (int*)(ws + 300800);           // 782 (pad 800)
  float2* pairS = (float2*)(ws + 301600);     // 782*4480 float2 = 7,006,720 f
  unsigned* pairD = (unsigned*)(ws + 7308320);// 782*4480 u32 = 3,503,360 f
  u16* hbf = (u16*)(ws + 10811680);           // 6.4M u16 = 3.2M f
  u16* Wbf = (u16*)(ws + 14011680);           // 16,384 u16
  // total ~14.02M floats = 56.1 MB

  const int* src = adj;
  const int* dst = adj + N_EDGES;

  k_prep<<<65, 256, 0, stream>>>(W, Wbf, sfill, dfill);
  k_linear<<<(N_NODES + 63) / 64, 256, 0, stream>>>(x, Wbf, b, a, hbf, s1v, s2v);
  k_place<<<dim3((N_EDGES + PEB - 1) / PEB, 2), PBT, 0, stream>>>(
      src, dst, s1v, s2v, sfill, dfill, pairS, pairD);
  k_denom<<<NBKT, 256, 0, stream>>>(dfill, pairD, denom_r);
  k_sortagg<<<NBKT, SAT, 0, stream>>>(sfill, pairS, denom_r, hbf, out);
}

// Round 6
// 356.347 us; speedup vs baseline: 1.3924x; 1.0256x over previous
//
#include <hip/hip_runtime.h>
#include <math.h>

#define N_NODES 100000
#define N_EDGES 3200000
#define IN_F 256
#define OUT_F 64
#define LRELU_ALPHA 0.2f
#define NBKT 782    // src buckets: 128 nodes each
#define CAP 4480    // src bucket capacity: mean 4096 + 6 sigma
#define NBKTD 98    // dst coarse buckets: 1024 nodes each
#define CAPD 34304  // dst bucket capacity: mean 32653 + ~9 sigma

typedef unsigned short u16;
typedef __attribute__((ext_vector_type(8))) short short8;
typedef __attribute__((ext_vector_type(4))) float floatx4;

__device__ inline u16 f2bf(float f) {  // RNE fp32 -> bf16
  unsigned u = __float_as_uint(f);
  u += 0x7FFFu + ((u >> 16) & 1u);
  return (u16)(u >> 16);
}
__device__ inline float bf2f(u16 h) {
  return __uint_as_float(((unsigned)h) << 16);
}

// ---------------------------------------------------------------------------
// prep: blocks 0..63 convert W to bf16; block 64 zeros fill ctrs;
// blocks 65..164 zero denom (100,000 floats, float4 stores)
// ---------------------------------------------------------------------------
__global__ __launch_bounds__(256) void k_prep(const float* __restrict__ W,
                                              u16* __restrict__ Wbf,
                                              int* __restrict__ sfill,
                                              int* __restrict__ dfill,
                                              float* __restrict__ denom) {
  if (blockIdx.x < 64) {
    int i = blockIdx.x * 256 + threadIdx.x;
    Wbf[i] = f2bf(W[i]);
  } else if (blockIdx.x == 64) {
    for (int i = threadIdx.x; i < 800; i += 256) {
      sfill[i] = 0;
      dfill[i] = 0;
    }
  } else {
    int i4 = (blockIdx.x - 65) * 256 + threadIdx.x;
    if (i4 < 25000) {
      ((float4*)denom)[i4] = make_float4(0.f, 0.f, 0.f, 0.f);
    }
  }
}

// ---------------------------------------------------------------------------
// linear via bf16 MFMA: h = x@W^T + b (stored bf16); s1 = h.a1; s2 = h.a2
// ---------------------------------------------------------------------------
__global__ __launch_bounds__(256) void k_linear(
    const float* __restrict__ x, const u16* __restrict__ Wbf,
    const float* __restrict__ b, const float* __restrict__ a,
    u16* __restrict__ hbf, float* __restrict__ s1, float* __restrict__ s2) {
  __shared__ u16 Wlds[64 * 264];

  const int t = threadIdx.x;
#pragma unroll
  for (int p = 0; p < 8; p++) {
    int c = p * 256 + t;
    int row = c >> 5;
    int kc = (c & 31) * 8;
    *(short8*)&Wlds[row * 264 + kc] = *(const short8*)&Wbf[row * 256 + kc];
  }
  __syncthreads();

  const int w = t >> 6;
  const int lane = t & 63;
  const int col = lane & 15;
  const int q = lane >> 4;
  const int m0 = blockIdx.x * 64 + w * 16;

  floatx4 acc[4];
#pragma unroll
  for (int nt = 0; nt < 4; nt++) acc[nt] = (floatx4){0.f, 0.f, 0.f, 0.f};

  int mrow = m0 + col;
  if (mrow > N_NODES - 1) mrow = N_NODES - 1;
  const float* xrow = x + (size_t)mrow * IN_F + q * 8;

#pragma unroll
  for (int kk = 0; kk < 8; kk++) {
    float4 f0 = *(const float4*)(xrow + kk * 32);
    float4 f1 = *(const float4*)(xrow + kk * 32 + 4);
    short8 af;
    af[0] = (short)f2bf(f0.x);
    af[1] = (short)f2bf(f0.y);
    af[2] = (short)f2bf(f0.z);
    af[3] = (short)f2bf(f0.w);
    af[4] = (short)f2bf(f1.x);
    af[5] = (short)f2bf(f1.y);
    af[6] = (short)f2bf(f1.z);
    af[7] = (short)f2bf(f1.w);
#pragma unroll
    for (int nt = 0; nt < 4; nt++) {
      short8 bfr = *(const short8*)&Wlds[(nt * 16 + col) * 264 + kk * 32 + q * 8];
      acc[nt] = __builtin_amdgcn_mfma_f32_16x16x32_bf16(af, bfr, acc[nt], 0, 0, 0);
    }
  }

  float bv[4], a1v[4], a2v[4];
#pragma unroll
  for (int nt = 0; nt < 4; nt++) {
    bv[nt] = b[nt * 16 + col];
    a1v[nt] = a[nt * 16 + col];
    a2v[nt] = a[OUT_F + nt * 16 + col];
  }
#pragma unroll
  for (int r = 0; r < 4; r++) {
    int node = m0 + q * 4 + r;
    float p1 = 0.f, p2 = 0.f;
#pragma unroll
    for (int nt = 0; nt < 4; nt++) {
      float hv = acc[nt][r] + bv[nt];
      if (node < N_NODES) hbf[(size_t)node * OUT_F + nt * 16 + col] = f2bf(hv);
      p1 = fmaf(hv, a1v[nt], p1);
      p2 = fmaf(hv, a2v[nt], p2);
    }
#pragma unroll
    for (int s = 1; s < 16; s <<= 1) {
      p1 += __shfl_xor(p1, s, 16);
      p2 += __shfl_xor(p2, s, 16);
    }
    if (col == 0 && node < N_NODES) {
      s1[node] = p1;
      s2[node] = p2;
    }
  }
}

// ---------------------------------------------------------------------------
// place: ex = exp(leakyrelu(s1[src]+s2[dst])); write into PADDED buckets.
// R6: single-atomic rank trick -- the counting atomicAdd's return value IS
// the scatter rank (saved in registers). Deletes the rank pass, the lc
// re-zero, and one barrier. D side uses COARSE 1024-node buckets: flush
// runs are ~42 entries (vs 5.2) -> ~1x write amp, 8x fewer reserve atomics.
// pairS = float2 (ex, d | (s&127)<<17)  src-bucketed (128-node)
// pairD = u32 (bf16(ex)<<16 | d&1023)   dst-bucketed (1024-node)
// ---------------------------------------------------------------------------
#define PBT 512
#define EPT_P 8
#define PEB (PBT * EPT_P)  // 4096 edges per block
__global__ __launch_bounds__(PBT) void k_place(
    const int* __restrict__ src, const int* __restrict__ dst,
    const float* __restrict__ s1, const float* __restrict__ s2,
    int* __restrict__ sfill, int* __restrict__ dfill,
    float2* __restrict__ pairS, unsigned* __restrict__ pairD) {
  __shared__ int lc[NBKT];     // histogram (counts after pass 1)
  __shared__ int ofs[NBKT];    // block-local stage offset
  __shared__ int gbase[NBKT];  // global target base (incl. bkt*cap)
  __shared__ int tot;          // block-local stage allocator
  __shared__ float2 stage[PEB];
  __shared__ u16 stageB[PEB];  // bucket id per stage entry

  const int t = threadIdx.x;
  const int side = blockIdx.y;  // 0 = S (src-bucket), 1 = D (dst-bucket)
  const int base = blockIdx.x * PEB + t;
  const int nb = side ? NBKTD : NBKT;

  float ex[EPT_P];
  int key[EPT_P];
  int bk[EPT_P];
  int rk[EPT_P];

  for (int i = t; i < nb; i += PBT) lc[i] = 0;
  if (t == 0) tot = 0;
  __syncthreads();

  // ---- compute + count (rank = return value) ----
#pragma unroll
  for (int j = 0; j < EPT_P; j++) {
    int e = base + j * PBT;
    if (e < N_EDGES) {
      int s = src[e];
      int d = dst[e];
      float v = s1[s] + s2[d];
      v = v > 0.f ? v : LRELU_ALPHA * v;
      ex[j] = __expf(v);
      if (side == 0) {
        key[j] = d | ((s & 127) << 17);
        bk[j] = s >> 7;
      } else {
        key[j] = d & 1023;
        bk[j] = d >> 10;
      }
      rk[j] = atomicAdd(&lc[bk[j]], 1);
    } else {
      bk[j] = -1;
    }
  }
  __syncthreads();

  // ---- reserve global + local ranges ----
  int* fill = side ? dfill : sfill;
  const int capb = side ? CAPD : CAP;
  for (int i = t; i < nb; i += PBT) {
    int c = lc[i];
    if (c) {
      gbase[i] = i * capb + atomicAdd(&fill[i], c);
      ofs[i] = atomicAdd(&tot, c);
    }
  }
  __syncthreads();
  const int nval = tot;  // # valid edges this block

  if (side == 0) {
    // ---- S: scatter to stage at saved rank ----
#pragma unroll
    for (int j = 0; j < EPT_P; j++) {
      if (bk[j] >= 0) {
        int idx = ofs[bk[j]] + rk[j];
        stage[idx] = make_float2(ex[j], __int_as_float(key[j]));
        stageB[idx] = (u16)bk[j];
      }
    }
    __syncthreads();
    // ---- S: coalesced flush ----
    for (int i = t; i < nval; i += PBT) {
      int bkt = stageB[i];
      pairS[gbase[bkt] + (i - ofs[bkt])] = stage[i];
    }
  } else {
    // ---- D: scatter to stage (packed u32) at saved rank ----
    unsigned* stg32 = (unsigned*)stage;
#pragma unroll
    for (int j = 0; j < EPT_P; j++) {
      if (bk[j] >= 0) {
        int idx = ofs[bk[j]] + rk[j];
        stg32[idx] = ((unsigned)f2bf(ex[j]) << 16) | (unsigned)key[j];
        stageB[idx] = (u16)bk[j];
      }
    }
    __syncthreads();
    // ---- D: coalesced flush ----
    for (int i = t; i < nval; i += PBT) {
      int bkt = stageB[i];
      pairD[gbase[bkt] + (i - ofs[bkt])] = stg32[i];
    }
  }
}

// ---------------------------------------------------------------------------
// denom: grid (NBKTD, 8). Each sub-block takes 1/8 of a coarse dst-bucket's
// fill range, accumulates 1024 LDS partial sums, then flushes nonzero slots
// with low-contention global atomicAdd (~8 adds/counter device-wide).
// denom[] holds the SUM; sortagg applies rcp.
// ---------------------------------------------------------------------------
#define DSUB 8
__global__ __launch_bounds__(256) void k_denom(const int* __restrict__ dfill,
                                               const unsigned* __restrict__ pairD,
                                               float* __restrict__ denom) {
  __shared__ float lacc[1024];
  const int t = threadIdx.x;
  const int c = blockIdx.x;
  const int sub = blockIdx.y;
  for (int i = t; i < 1024; i += 256) lacc[i] = 0.f;
  __syncthreads();
  const int fill = dfill[c];
  const int b0 = c * CAPD + fill * sub / DSUB;
  const int b1 = c * CAPD + fill * (sub + 1) / DSUB;
  for (int i = b0 + t; i < b1; i += 256) {
    unsigned u = pairD[i];
    atomicAdd(&lacc[u & 1023], __uint_as_float(u & 0xFFFF0000u));
  }
  __syncthreads();
  for (int i = t; i < 1024; i += 256) {
    float v = lacc[i];
    if (v != 0.f) {
      int node = c * 1024 + i;
      if (node < N_NODES) atomicAdd(&denom[node], v);
    }
  }
}

// ---------------------------------------------------------------------------
// sortagg: FUSED sort + aggregate. Block (1024 thr) per src-bucket.
// R6: histogram pass keeps pair values + rank (atomicAdd return) in
// REGISTERS (static-indexed, 5 slots) -> no pairS re-read, no cursor
// atomics. Scatter att-folded pairs into LDS at nbeg[sl]+rank, then
// aggregate: 16 lanes/node, float4 acc, hbf row gather, ELU, write out.
// ---------------------------------------------------------------------------
#define SAT 1024
#define SMAX 5  // ceil(CAP / SAT)
__global__ __launch_bounds__(SAT) void k_sortagg(
    const int* __restrict__ sfill, const float2* __restrict__ pairS,
    const float* __restrict__ denom, const u16* __restrict__ hbf,
    float* __restrict__ out) {
  __shared__ float2 stg[CAP];
  __shared__ int lcnt[128];
  __shared__ int nbeg[128];
  __shared__ int nend[128];
  __shared__ int w0tot;
  const int t = threadIdx.x;
  const int bkt = blockIdx.x;

  if (t < 128) lcnt[t] = 0;
  __syncthreads();

  const int gbeg = bkt * CAP;
  const int ne = sfill[bkt];

  // ---- histogram; keep value + rank in registers ----
  float2 pr[SMAX];
  int rk[SMAX];
#pragma unroll
  for (int k = 0; k < SMAX; k++) {
    int i = t + k * SAT;
    if (i < ne) {
      float2 p = pairS[gbeg + i];
      pr[k] = p;
      rk[k] = atomicAdd(&lcnt[(__float_as_int(p.y) >> 17) & 127], 1);
    }
  }
  __syncthreads();

  // ---- scan (128 entries over 2 waves) ----
  const int lane = t & 63;
  int v = (t < 128) ? lcnt[t] : 0;
  int val = v;
#pragma unroll
  for (int o = 1; o < 64; o <<= 1) {
    int u = __shfl_up(val, o, 64);
    if (lane >= o) val += u;
  }
  if (t == 63) w0tot = val;
  __syncthreads();
  if (t < 128) {
    int excl = val - v + ((t >= 64) ? w0tot : 0);
    nbeg[t] = excl;
    nend[t] = excl + v;
  }
  __syncthreads();

  // ---- scatter into LDS stage with att folded (no atomics) ----
#pragma unroll
  for (int k = 0; k < SMAX; k++) {
    int i = t + k * SAT;
    if (i < ne) {
      int pkv = __float_as_int(pr[k].y);
      int sl = (pkv >> 17) & 127;
      int d = pkv & 0x1FFFF;
      float att = pr[k].x * __builtin_amdgcn_rcpf(denom[d]);
      stg[nbeg[sl] + rk[k]] = make_float2(att, __int_as_float(d));
    }
  }
  __syncthreads();

  // ---- aggregate: 64 groups of 16 lanes; each group 2 nodes ----
  const int G = t >> 4;   // 0..63
  const int sl = t & 15;  // feature quad
  for (int nl = G; nl < 128; nl += 64) {
    int node = bkt * 128 + nl;
    int i = nbeg[nl];
    const int e0 = nend[nl];
    float4 acc = make_float4(0.f, 0.f, 0.f, 0.f);
    for (; i + 1 < e0; i += 2) {
      float2 p0 = stg[i];
      float2 p1 = stg[i + 1];
      int d0 = __float_as_int(p0.y);
      int d1 = __float_as_int(p1.y);
      ushort4 q0 = *(const ushort4*)&hbf[(size_t)d0 * OUT_F + sl * 4];
      ushort4 q1 = *(const ushort4*)&hbf[(size_t)d1 * OUT_F + sl * 4];
      acc.x = fmaf(p0.x, bf2f(q0.x), acc.x);
      acc.y = fmaf(p0.x, bf2f(q0.y), acc.y);
      acc.z = fmaf(p0.x, bf2f(q0.z), acc.z);
      acc.w = fmaf(p0.x, bf2f(q0.w), acc.w);
      acc.x = fmaf(p1.x, bf2f(q1.x), acc.x);
      acc.y = fmaf(p1.x, bf2f(q1.y), acc.y);
      acc.z = fmaf(p1.x, bf2f(q1.z), acc.z);
      acc.w = fmaf(p1.x, bf2f(q1.w), acc.w);
    }
    if (i < e0) {
      float2 p = stg[i];
      int d = __float_as_int(p.y);
      ushort4 q = *(const ushort4*)&hbf[(size_t)d * OUT_F + sl * 4];
      acc.x = fmaf(p.x, bf2f(q.x), acc.x);
      acc.y = fmaf(p.x, bf2f(q.y), acc.y);
      acc.z = fmaf(p.x, bf2f(q.z), acc.z);
      acc.w = fmaf(p.x, bf2f(q.w), acc.w);
    }
    if (node < N_NODES) {
      float4 o;
      o.x = acc.x > 0.f ? acc.x : expm1f(acc.x);
      o.y = acc.y > 0.f ? acc.y : expm1f(acc.y);
      o.z = acc.z > 0.f ? acc.z : expm1f(acc.z);
      o.w = acc.w > 0.f ? acc.w : expm1f(acc.w);
      *(float4*)(out + (size_t)node * OUT_F + sl * 4) = o;
    }
  }
}

// ---------------------------------------------------------------------------
extern "C" void kernel_launch(void* const* d_in, const int* in_sizes, int n_in,
                              void* d_out, int out_size, void* d_ws,
                              size_t ws_size, hipStream_t stream) {
  const int* adj = (const int*)d_in[0];
  const float* x = (const float*)d_in[1];
  const float* W = (const float*)d_in[2];
  const float* b = (const float*)d_in[3];
  const float* a = (const float*)d_in[4];
  float* out = (float*)d_out;

  float* ws = (float*)d_ws;
  float* s1v = ws;                            // 100,000
  float* s2v = ws + 100000;                   // 100,000
  float* denom = ws + 200000;                 // 100,000 (zeroed in prep)
  int* sfill = (int*)(ws + 300000);           // 782 (pad 800)
  int* dfill = (int*)(ws + 300800);           // 98 (pad 800)
  float2* pairS = (float2*)(ws + 301600);     // 782*4480 float2 = 7,006,720 f
  unsigned* pairD = (unsigned*)(ws + 7308320);// 98*34304 u32 = 3,361,792 f
  u16* hbf = (u16*)(ws + 10670112);           // 6.4M u16 = 3.2M f
  u16* Wbf = (u16*)(ws + 13870112);           // 16,384 u16 = 8,192 f
  // total ~13.88M floats = 55.5 MB

  const int* src = adj;
  const int* dst = adj + N_EDGES;

  k_prep<<<165, 256, 0, stream>>>(W, Wbf, sfill, dfill, denom);
  k_linear<<<(N_NODES + 63) / 64, 256, 0, stream>>>(x, Wbf, b, a, hbf, s1v, s2v);
  k_place<<<dim3((N_EDGES + PEB - 1) / PEB, 2), PBT, 0, stream>>>(
      src, dst, s1v, s2v, sfill, dfill, pairS, pairD);
  k_denom<<<dim3(NBKTD, DSUB), 256, 0, stream>>>(dfill, pairD, denom);
  k_sortagg<<<NBKT, SAT, 0, stream>>>(sfill, pairS, denom, hbf, out);
}

// Round 7
// 351.277 us; speedup vs baseline: 1.4125x; 1.0144x over previous
//
#include <hip/hip_runtime.h>
#include <math.h>

#define N_NODES 100000
#define N_EDGES 3200000
#define IN_F 256
#define OUT_F 64
#define LRELU_ALPHA 0.2f
#define NBKT 782    // src buckets: 128 nodes each
#define CAP 4480    // src bucket capacity: mean 4096 + 6 sigma
#define NBKTD 98    // dst coarse buckets: 1024 nodes each
#define CAPD 34304  // dst bucket capacity: mean 32653 + ~9 sigma

typedef unsigned short u16;
typedef __attribute__((ext_vector_type(8))) short short8;
typedef __attribute__((ext_vector_type(4))) float floatx4;

__device__ inline u16 f2bf(float f) {  // RNE fp32 -> bf16
  unsigned u = __float_as_uint(f);
  u += 0x7FFFu + ((u >> 16) & 1u);
  return (u16)(u >> 16);
}
__device__ inline float bf2f(u16 h) {
  return __uint_as_float(((unsigned)h) << 16);
}

// ---------------------------------------------------------------------------
// prep: blocks 0..63 convert W to bf16; block 64 zeros fill ctrs;
// blocks 65..164 zero denom (100,000 floats, float4 stores)
// ---------------------------------------------------------------------------
__global__ __launch_bounds__(256) void k_prep(const float* __restrict__ W,
                                              u16* __restrict__ Wbf,
                                              int* __restrict__ sfill,
                                              int* __restrict__ dfill,
                                              float* __restrict__ denom) {
  if (blockIdx.x < 64) {
    int i = blockIdx.x * 256 + threadIdx.x;
    Wbf[i] = f2bf(W[i]);
  } else if (blockIdx.x == 64) {
    for (int i = threadIdx.x; i < 800; i += 256) {
      sfill[i] = 0;
      dfill[i] = 0;
    }
  } else {
    int i4 = (blockIdx.x - 65) * 256 + threadIdx.x;
    if (i4 < 25000) {
      ((float4*)denom)[i4] = make_float4(0.f, 0.f, 0.f, 0.f);
    }
  }
}

// ---------------------------------------------------------------------------
// linear via bf16 MFMA: h = x@W^T + b (stored bf16); s1 = h.a1; s2 = h.a2
// ---------------------------------------------------------------------------
__global__ __launch_bounds__(256) void k_linear(
    const float* __restrict__ x, const u16* __restrict__ Wbf,
    const float* __restrict__ b, const float* __restrict__ a,
    u16* __restrict__ hbf, float* __restrict__ s1, float* __restrict__ s2) {
  __shared__ u16 Wlds[64 * 264];

  const int t = threadIdx.x;
#pragma unroll
  for (int p = 0; p < 8; p++) {
    int c = p * 256 + t;
    int row = c >> 5;
    int kc = (c & 31) * 8;
    *(short8*)&Wlds[row * 264 + kc] = *(const short8*)&Wbf[row * 256 + kc];
  }
  __syncthreads();

  const int w = t >> 6;
  const int lane = t & 63;
  const int col = lane & 15;
  const int q = lane >> 4;
  const int m0 = blockIdx.x * 64 + w * 16;

  floatx4 acc[4];
#pragma unroll
  for (int nt = 0; nt < 4; nt++) acc[nt] = (floatx4){0.f, 0.f, 0.f, 0.f};

  int mrow = m0 + col;
  if (mrow > N_NODES - 1) mrow = N_NODES - 1;
  const float* xrow = x + (size_t)mrow * IN_F + q * 8;

#pragma unroll
  for (int kk = 0; kk < 8; kk++) {
    float4 f0 = *(const float4*)(xrow + kk * 32);
    float4 f1 = *(const float4*)(xrow + kk * 32 + 4);
    short8 af;
    af[0] = (short)f2bf(f0.x);
    af[1] = (short)f2bf(f0.y);
    af[2] = (short)f2bf(f0.z);
    af[3] = (short)f2bf(f0.w);
    af[4] = (short)f2bf(f1.x);
    af[5] = (short)f2bf(f1.y);
    af[6] = (short)f2bf(f1.z);
    af[7] = (short)f2bf(f1.w);
#pragma unroll
    for (int nt = 0; nt < 4; nt++) {
      short8 bfr = *(const short8*)&Wlds[(nt * 16 + col) * 264 + kk * 32 + q * 8];
      acc[nt] = __builtin_amdgcn_mfma_f32_16x16x32_bf16(af, bfr, acc[nt], 0, 0, 0);
    }
  }

  float bv[4], a1v[4], a2v[4];
#pragma unroll
  for (int nt = 0; nt < 4; nt++) {
    bv[nt] = b[nt * 16 + col];
    a1v[nt] = a[nt * 16 + col];
    a2v[nt] = a[OUT_F + nt * 16 + col];
  }
#pragma unroll
  for (int r = 0; r < 4; r++) {
    int node = m0 + q * 4 + r;
    float p1 = 0.f, p2 = 0.f;
#pragma unroll
    for (int nt = 0; nt < 4; nt++) {
      float hv = acc[nt][r] + bv[nt];
      if (node < N_NODES) hbf[(size_t)node * OUT_F + nt * 16 + col] = f2bf(hv);
      p1 = fmaf(hv, a1v[nt], p1);
      p2 = fmaf(hv, a2v[nt], p2);
    }
#pragma unroll
    for (int s = 1; s < 16; s <<= 1) {
      p1 += __shfl_xor(p1, s, 16);
      p2 += __shfl_xor(p2, s, 16);
    }
    if (col == 0 && node < N_NODES) {
      s1[node] = p1;
      s2[node] = p2;
    }
  }
}

// ---------------------------------------------------------------------------
// place: ex = exp(leakyrelu(s1[src]+s2[dst])); write into PADDED buckets.
// R7: explicit MLP -- phase 1 split into batched passes (all adj loads,
// then all s1/s2 gathers, then math, then LDS atomics) so 16 gathers fly
// concurrently instead of serialized dep chains. launch_bounds(512,6)
// raises the VGPR cap to ~80 (was 40) to hold the in-flight state.
// pairS = float2 (ex, d | (s&127)<<17)  src-bucketed (128-node)
// pairD = u32 (bf16(ex)<<16 | d&1023)   dst-bucketed (1024-node)
// ---------------------------------------------------------------------------
#define PBT 512
#define EPT_P 8
#define PEB (PBT * EPT_P)  // 4096 edges per block
__global__ __launch_bounds__(PBT, 6) void k_place(
    const int* __restrict__ src, const int* __restrict__ dst,
    const float* __restrict__ s1, const float* __restrict__ s2,
    int* __restrict__ sfill, int* __restrict__ dfill,
    float2* __restrict__ pairS, unsigned* __restrict__ pairD) {
  __shared__ int lc[NBKT];     // histogram (counts after pass 1)
  __shared__ int ofs[NBKT];    // block-local stage offset
  __shared__ int gbase[NBKT];  // global target base (incl. bkt*cap)
  __shared__ int tot;          // block-local stage allocator
  __shared__ float2 stage[PEB];
  __shared__ u16 stageB[PEB];  // bucket id per stage entry

  const int t = threadIdx.x;
  const int side = blockIdx.y;  // 0 = S (src-bucket), 1 = D (dst-bucket)
  const int base = blockIdx.x * PEB + t;
  const int nb = side ? NBKTD : NBKT;

  for (int i = t; i < nb; i += PBT) lc[i] = 0;
  if (t == 0) tot = 0;
  __syncthreads();

  // ---- pass A: all adj loads in flight ----
  int sa[EPT_P], da[EPT_P];
#pragma unroll
  for (int j = 0; j < EPT_P; j++) {
    int e = base + j * PBT;
    int ec = e < N_EDGES ? e : N_EDGES - 1;
    sa[j] = src[ec];
    da[j] = dst[ec];
  }
  // ---- pass B: all s1/s2 gathers in flight ----
  float g1[EPT_P], g2[EPT_P];
#pragma unroll
  for (int j = 0; j < EPT_P; j++) {
    g1[j] = s1[sa[j]];
    g2[j] = s2[da[j]];
  }
  // ---- pass C: math + keys ----
  float ex[EPT_P];
  int key[EPT_P], bk[EPT_P], rk[EPT_P];
#pragma unroll
  for (int j = 0; j < EPT_P; j++) {
    float v = g1[j] + g2[j];
    v = v > 0.f ? v : LRELU_ALPHA * v;
    ex[j] = __expf(v);
    if (side == 0) {
      key[j] = da[j] | ((sa[j] & 127) << 17);
      bk[j] = sa[j] >> 7;
    } else {
      key[j] = da[j] & 1023;
      bk[j] = da[j] >> 10;
    }
    if (base + j * PBT >= N_EDGES) bk[j] = -1;
  }
  // ---- pass D: count (rank = return value) ----
#pragma unroll
  for (int j = 0; j < EPT_P; j++) {
    if (bk[j] >= 0) rk[j] = atomicAdd(&lc[bk[j]], 1);
  }
  __syncthreads();

  // ---- reserve global + local ranges ----
  int* fill = side ? dfill : sfill;
  const int capb = side ? CAPD : CAP;
  for (int i = t; i < nb; i += PBT) {
    int c = lc[i];
    if (c) {
      gbase[i] = i * capb + atomicAdd(&fill[i], c);
      ofs[i] = atomicAdd(&tot, c);
    }
  }
  __syncthreads();
  const int nval = tot;  // # valid edges this block

  if (side == 0) {
    // ---- S: scatter to stage at saved rank ----
#pragma unroll
    for (int j = 0; j < EPT_P; j++) {
      if (bk[j] >= 0) {
        int idx = ofs[bk[j]] + rk[j];
        stage[idx] = make_float2(ex[j], __int_as_float(key[j]));
        stageB[idx] = (u16)bk[j];
      }
    }
    __syncthreads();
    // ---- S: coalesced flush ----
    for (int i = t; i < nval; i += PBT) {
      int bkt = stageB[i];
      pairS[gbase[bkt] + (i - ofs[bkt])] = stage[i];
    }
  } else {
    // ---- D: scatter to stage (packed u32) at saved rank ----
    unsigned* stg32 = (unsigned*)stage;
#pragma unroll
    for (int j = 0; j < EPT_P; j++) {
      if (bk[j] >= 0) {
        int idx = ofs[bk[j]] + rk[j];
        stg32[idx] = ((unsigned)f2bf(ex[j]) << 16) | (unsigned)key[j];
        stageB[idx] = (u16)bk[j];
      }
    }
    __syncthreads();
    // ---- D: coalesced flush ----
    for (int i = t; i < nval; i += PBT) {
      int bkt = stageB[i];
      pairD[gbase[bkt] + (i - ofs[bkt])] = stg32[i];
    }
  }
}

// ---------------------------------------------------------------------------
// denom: grid (NBKTD, 8). Each sub-block takes 1/8 of a coarse dst-bucket's
// fill range, accumulates 1024 LDS partial sums, then flushes nonzero slots
// with low-contention global atomicAdd (~8 adds/counter device-wide).
// denom[] holds the SUM; sortagg applies rcp.
// ---------------------------------------------------------------------------
#define DSUB 8
__global__ __launch_bounds__(256) void k_denom(const int* __restrict__ dfill,
                                               const unsigned* __restrict__ pairD,
                                               float* __restrict__ denom) {
  __shared__ float lacc[1024];
  const int t = threadIdx.x;
  const int c = blockIdx.x;
  const int sub = blockIdx.y;
  for (int i = t; i < 1024; i += 256) lacc[i] = 0.f;
  __syncthreads();
  const int fill = dfill[c];
  const int b0 = c * CAPD + fill * sub / DSUB;
  const int b1 = c * CAPD + fill * (sub + 1) / DSUB;
  for (int i = b0 + t; i < b1; i += 256) {
    unsigned u = pairD[i];
    atomicAdd(&lacc[u & 1023], __uint_as_float(u & 0xFFFF0000u));
  }
  __syncthreads();
  for (int i = t; i < 1024; i += 256) {
    float v = lacc[i];
    if (v != 0.f) {
      int node = c * 1024 + i;
      if (node < N_NODES) atomicAdd(&denom[node], v);
    }
  }
}

// ---------------------------------------------------------------------------
// sortagg: FUSED sort + aggregate. Block (1024 thr) per src-bucket.
// R7: batched loads -- 5 pairS reads issued together, 5 denom gathers
// issued together (explicit MLP), then scatter. Aggregate unchanged.
// ---------------------------------------------------------------------------
#define SAT 1024
#define SMAX 5  // ceil(CAP / SAT)
__global__ __launch_bounds__(SAT) void k_sortagg(
    const int* __restrict__ sfill, const float2* __restrict__ pairS,
    const float* __restrict__ denom, const u16* __restrict__ hbf,
    float* __restrict__ out) {
  __shared__ float2 stg[CAP];
  __shared__ int lcnt[128];
  __shared__ int nbeg[128];
  __shared__ int nend[128];
  __shared__ int w0tot;
  const int t = threadIdx.x;
  const int bkt = blockIdx.x;

  if (t < 128) lcnt[t] = 0;
  __syncthreads();

  const int gbeg = bkt * CAP;
  const int ne = sfill[bkt];

  // ---- batched pairS loads ----
  float2 pr[SMAX];
#pragma unroll
  for (int k = 0; k < SMAX; k++) {
    int i = t + k * SAT;
    if (i < ne) pr[k] = pairS[gbeg + i];
  }
  // ---- histogram (rank = return value) ----
  int rk[SMAX];
#pragma unroll
  for (int k = 0; k < SMAX; k++) {
    int i = t + k * SAT;
    if (i < ne) rk[k] = atomicAdd(&lcnt[(__float_as_int(pr[k].y) >> 17) & 127], 1);
  }
  __syncthreads();

  // ---- scan (128 entries over 2 waves) ----
  const int lane = t & 63;
  int v = (t < 128) ? lcnt[t] : 0;
  int val = v;
#pragma unroll
  for (int o = 1; o < 64; o <<= 1) {
    int u = __shfl_up(val, o, 64);
    if (lane >= o) val += u;
  }
  if (t == 63) w0tot = val;
  __syncthreads();
  if (t < 128) {
    int excl = val - v + ((t >= 64) ? w0tot : 0);
    nbeg[t] = excl;
    nend[t] = excl + v;
  }
  __syncthreads();

  // ---- batched denom gathers ----
  float dn[SMAX];
#pragma unroll
  for (int k = 0; k < SMAX; k++) {
    int i = t + k * SAT;
    if (i < ne) dn[k] = denom[__float_as_int(pr[k].y) & 0x1FFFF];
  }
  // ---- scatter into LDS stage with att folded (no atomics) ----
#pragma unroll
  for (int k = 0; k < SMAX; k++) {
    int i = t + k * SAT;
    if (i < ne) {
      int pkv = __float_as_int(pr[k].y);
      int sl = (pkv >> 17) & 127;
      int d = pkv & 0x1FFFF;
      float att = pr[k].x * __builtin_amdgcn_rcpf(dn[k]);
      stg[nbeg[sl] + rk[k]] = make_float2(att, __int_as_float(d));
    }
  }
  __syncthreads();

  // ---- aggregate: 64 groups of 16 lanes; each group 2 nodes ----
  const int G = t >> 4;   // 0..63
  const int sl = t & 15;  // feature quad
  for (int nl = G; nl < 128; nl += 64) {
    int node = bkt * 128 + nl;
    int i = nbeg[nl];
    const int e0 = nend[nl];
    float4 acc = make_float4(0.f, 0.f, 0.f, 0.f);
    for (; i + 1 < e0; i += 2) {
      float2 p0 = stg[i];
      float2 p1 = stg[i + 1];
      int d0 = __float_as_int(p0.y);
      int d1 = __float_as_int(p1.y);
      ushort4 q0 = *(const ushort4*)&hbf[(size_t)d0 * OUT_F + sl * 4];
      ushort4 q1 = *(const ushort4*)&hbf[(size_t)d1 * OUT_F + sl * 4];
      acc.x = fmaf(p0.x, bf2f(q0.x), acc.x);
      acc.y = fmaf(p0.x, bf2f(q0.y), acc.y);
      acc.z = fmaf(p0.x, bf2f(q0.z), acc.z);
      acc.w = fmaf(p0.x, bf2f(q0.w), acc.w);
      acc.x = fmaf(p1.x, bf2f(q1.x), acc.x);
      acc.y = fmaf(p1.x, bf2f(q1.y), acc.y);
      acc.z = fmaf(p1.x, bf2f(q1.z), acc.z);
      acc.w = fmaf(p1.x, bf2f(q1.w), acc.w);
    }
    if (i < e0) {
      float2 p = stg[i];
      int d = __float_as_int(p.y);
      ushort4 q = *(const ushort4*)&hbf[(size_t)d * OUT_F + sl * 4];
      acc.x = fmaf(p.x, bf2f(q.x), acc.x);
      acc.y = fmaf(p.x, bf2f(q.y), acc.y);
      acc.z = fmaf(p.x, bf2f(q.z), acc.z);
      acc.w = fmaf(p.x, bf2f(q.w), acc.w);
    }
    if (node < N_NODES) {
      float4 o;
      o.x = acc.x > 0.f ? acc.x : expm1f(acc.x);
      o.y = acc.y > 0.f ? acc.y : expm1f(acc.y);
      o.z = acc.z > 0.f ? acc.z : expm1f(acc.z);
      o.w = acc.w > 0.f ? acc.w : expm1f(acc.w);
      *(float4*)(out + (size_t)node * OUT_F + sl * 4) = o;
    }
  }
}

// ---------------------------------------------------------------------------
extern "C" void kernel_launch(void* const* d_in, const int* in_sizes, int n_in,
                              void* d_out, int out_size, void* d_ws,
                              size_t ws_size, hipStream_t stream) {
  const int* adj = (const int*)d_in[0];
  const float* x = (const float*)d_in[1];
  const float* W = (const float*)d_in[2];
  const float* b = (const float*)d_in[3];
  const float* a = (const float*)d_in[4];
  float* out = (float*)d_out;

  float* ws = (float*)d_ws;
  float* s1v = ws;                            // 100,000
  float* s2v = ws + 100000;                   // 100,000
  float* denom = ws + 200000;                 // 100,000 (zeroed in prep)
  int* sfill = (int*)(ws + 300000);           // 782 (pad 800)
  int* dfill = (int*)(ws + 300800);           // 98 (pad 800)
  float2* pairS = (float2*)(ws + 301600);     // 782*4480 float2 = 7,006,720 f
  unsigned* pairD = (unsigned*)(ws + 7308320);// 98*34304 u32 = 3,361,792 f
  u16* hbf = (u16*)(ws + 10670112);           // 6.4M u16 = 3.2M f
  u16* Wbf = (u16*)(ws + 13870112);           // 16,384 u16 = 8,192 f
  // total ~13.88M floats = 55.5 MB

  const int* src = adj;
  const int* dst = adj + N_EDGES;

  k_prep<<<165, 256, 0, stream>>>(W, Wbf, sfill, dfill, denom);
  k_linear<<<(N_NODES + 63) / 64, 256, 0, stream>>>(x, Wbf, b, a, hbf, s1v, s2v);
  k_place<<<dim3((N_EDGES + PEB - 1) / PEB, 2), PBT, 0, stream>>>(
      src, dst, s1v, s2v, sfill, dfill, pairS, pairD);
  k_denom<<<dim3(NBKTD, DSUB), 256, 0, stream>>>(dfill, pairD, denom);
  k_sortagg<<<NBKT, SAT, 0, stream>>>(sfill, pairS, denom, hbf, out);
}